// Round 5
// baseline (540.230 us; speedup 1.0000x reference)
//
#include <hip/hip_runtime.h>
#include <hip/hip_bf16.h>

using bf16 = __hip_bfloat16;
typedef __attribute__((ext_vector_type(8))) short short8;
typedef __attribute__((ext_vector_type(4))) float f32x4;

__device__ __forceinline__ float b2f(bf16 v){ return __bfloat162float(v); }
__device__ __forceinline__ float sigf(float v){ return 1.f/(1.f + __expf(-v)); }
__device__ __forceinline__ float ldv(const float* p, int i){ return p[i]; }
__device__ __forceinline__ float ldv(const bf16* p, int i){ return b2f(p[i]); }
__device__ __forceinline__ void stv(float* p, int i, float v){ p[i] = v; }
__device__ __forceinline__ void stv(bf16* p, int i, float v){ p[i] = __float2bfloat16(v); }

// ---------------------------------------------------------------------------
// K0: dtype detect. flag=1 => inputs are f32.
// ---------------------------------------------------------------------------
__global__ __launch_bounds__(256) void k_detect(const unsigned short* xs, int* flag){
  __shared__ int cnt;
  if (threadIdx.x == 0) cnt = 0;
  __syncthreads();
  int local = 0;
  for (int i = threadIdx.x; i < 16384; i += 256){
    if (((xs[i] >> 7) & 0xFF) == 0xFF) local++;
  }
  if (local) atomicAdd(&cnt, local);
  __syncthreads();
  if (threadIdx.x == 0) *flag = (cnt > 0) ? 1 : 0;
}

// ---------------------------------------------------------------------------
// K0b: canonicalize params. slots 0-17: fp32 in cpar; 18: w_def->bf16;
// 19: w_off->bf16 padded 18->32 rows; 20: w_g1->bf16; 21: w_cross->bf16;
// 22: w_out->bf16. grid (96, 23).
// ---------------------------------------------------------------------------
struct ParamSrc { const void* p[18]; };

__global__ __launch_bounds__(256) void k_convert(ParamSrc ps, const int* flagp,
    float* cpar, bf16* wdefb, bf16* woffb, bf16* wg1b, bf16* wcrossb, bf16* woutb){
  static constexpr int n[23]   = {41472,18,147456,131072,147456,64,64,64,64,64,
                                  16384,256,65536,256,256,256,256,256,
                                  147456,73728,147456,131072,65536};
  static constexpr int off[18] = {0,41472,41504,188960,320032,467488,467552,467616,
                                  467680,467744,467808,484192,484448,549984,550240,
                                  550496,550752,551008};
  const int s = blockIdx.y;
  const bool f32 = (*flagp != 0);
  if (s >= 18){
    static constexpr int srcs[5] = {2, 0, 4, 3, 12};
    const int src_slot = srcs[s - 18];
    bf16* dst = (s == 18) ? wdefb : (s == 19) ? woffb : (s == 20) ? wg1b
              : (s == 21) ? wcrossb : woutb;
    const int nsrc = (s == 19) ? 41472 : n[s];
    if (f32){
      const float* src = (const float*)ps.p[src_slot];
      for (int i = blockIdx.x * 256 + threadIdx.x; i < n[s]; i += gridDim.x * 256)
        dst[i] = (i < nsrc) ? __float2bfloat16(src[i]) : __float2bfloat16(0.f);
    } else {
      const bf16* src = (const bf16*)ps.p[src_slot];
      for (int i = blockIdx.x * 256 + threadIdx.x; i < n[s]; i += gridDim.x * 256)
        dst[i] = (i < nsrc) ? src[i] : __float2bfloat16(0.f);
    }
    return;
  }
  float* dst = cpar + off[s];
  if (f32){
    const float* src = (const float*)ps.p[s];
    for (int i = blockIdx.x * 256 + threadIdx.x; i < n[s]; i += gridDim.x * 256)
      dst[i] = src[i];
  } else {
    const bf16* src = (const bf16*)ps.p[s];
    for (int i = blockIdx.x * 256 + threadIdx.x; i < n[s]; i += gridDim.x * 256)
      dst[i] = b2f(src[i]);
  }
}

// ---------------------------------------------------------------------------
// Generic 3x3 pad=1 conv via im2col + MFMA. Block = one image row (64 px),
// 256 thr, grid 256 (b*64+y). K=2304 in 8 chunks of 288 (32 ch x 9 taps).
// LDS cols layout [k][pos] (pad 68): pixel-pair-packed b32 writes are
// conflict-free; B-frag u16 reads are 2-way (free). A-frags: bf16 weights
// from global (L2-resident). COT = #16-co m-tiles. EPI: BN+SiLU epilogue.
// ---------------------------------------------------------------------------
template<typename T, int COT, bool EPI>
__device__ __forceinline__ void conv3_body(const T* __restrict__ xin,
    const bf16* __restrict__ wb, const float* __restrict__ cbv,
    const float* __restrict__ gam, const float* __restrict__ bet,
    const float* __restrict__ mea, const float* __restrict__ var,
    float* __restrict__ outp, int co_lim, unsigned short* cols){
  const int bx = blockIdx.x;
  const int b = bx >> 6, y = bx & 63;
  const int t = threadIdx.x;
  const int l = t & 63, w = t >> 6;
  const int lm = l & 15, lq = l >> 4;
  const int pos2 = t & 31, kq = t >> 5;
  unsigned int* cols32 = (unsigned int*)cols;
  f32x4 acc[COT];
  #pragma unroll
  for (int m = 0; m < COT; m++) acc[m] = (f32x4){0.f,0.f,0.f,0.f};

  for (int cc = 0; cc < 256; cc += 32){
    __syncthreads();
    // ---- gather: 4 channels (kq*4..+4) x 9 taps x pixel pair (2*pos2, +1)
    #pragma unroll
    for (int c8 = 0; c8 < 4; c8++){
      const int c_local = kq * 4 + c8;
      const T* xc = xin + (b * 256 + cc + c_local) * 4096;
      #pragma unroll
      for (int tap = 0; tap < 9; tap++){
        const int ti = tap / 3, tj = tap % 3;
        const int yy = y + ti - 1;
        const int px0 = 2 * pos2 + tj - 1;
        const bool vy = (unsigned)yy < 64u;
        float v0 = (vy && (unsigned)px0 < 64u) ? ldv(xc, yy * 64 + px0) : 0.f;
        float v1 = (vy && (unsigned)(px0 + 1) < 64u) ? ldv(xc, yy * 64 + px0 + 1) : 0.f;
        bf16 h0 = __float2bfloat16(v0), h1 = __float2bfloat16(v1);
        unsigned int packed = (unsigned int)*(unsigned short*)&h0
                            | ((unsigned int)*(unsigned short*)&h1 << 16);
        cols32[(c_local * 9 + tap) * 34 + pos2] = packed;
      }
    }
    __syncthreads();
    // ---- MFMA: 9 ksteps of 32 over this chunk
    #pragma unroll
    for (int kk = 0; kk < 288; kk += 32){
      short8 bfr;
      #pragma unroll
      for (int j = 0; j < 8; j++)
        bfr[j] = (short)cols[(kk + lq * 8 + j) * 68 + w * 16 + lm];
      #pragma unroll
      for (int m = 0; m < COT; m++){
        const bf16* ap = wb + (m * 16 + lm) * 2304 + cc * 9 + kk + lq * 8;
        short8 afr = *(const short8*)ap;
        acc[m] = __builtin_amdgcn_mfma_f32_16x16x32_bf16(afr, bfr, acc[m], 0, 0, 0);
      }
    }
  }
  // ---- epilogue: D col=lane&15 (pixel), row=(lane>>4)*4+reg (co)
  const int p = y * 64 + w * 16 + lm;
  #pragma unroll
  for (int m = 0; m < COT; m++){
    #pragma unroll
    for (int r = 0; r < 4; r++){
      const int co = m * 16 + lq * 4 + r;
      if (co >= co_lim) continue;
      float v = acc[m][r] + cbv[co];
      if constexpr (EPI){
        float inv = gam[co] * rsqrtf(var[co] + 1e-5f);
        v = v * inv + (bet[co] - mea[co] * inv);
        v = v * sigf(v);
      }
      outp[(b * co_lim + co) * 4096 + p] = v;
    }
  }
}

__global__ __launch_bounds__(256) void k_coff_m(const void* x, const int* flagp,
    const bf16* woffb, const float* cb, float* offc){
  __shared__ __align__(16) unsigned short cols[288 * 68];
  if (*flagp) conv3_body<float, 2, false>((const float*)x, woffb, cb,
                  nullptr, nullptr, nullptr, nullptr, offc, 18, cols);
  else        conv3_body<bf16, 2, false>((const bf16*)x, woffb, cb,
                  nullptr, nullptr, nullptr, nullptr, offc, 18, cols);
}

__global__ __launch_bounds__(256) void k_g1_m(const float* xdense,
    const bf16* wg1b, const float* cb, const float* gam, const float* bet,
    const float* mea, const float* var, float* abuf){
  __shared__ __align__(16) unsigned short cols[288 * 68];
  conv3_body<float, 4, true>(xdense, wg1b, cb, gam, bet, mea, var, abuf, 64, cols);
}

// ---------------------------------------------------------------------------
// K2a: deform GATHER — no LDS, no barriers, no MFMA. Full-occupancy
// latency-bound gather writing im2col matrix to GLOBAL as bf16.
// Layout: colsg[b][g][k=cg*9+tap (576)][p (4096)].
// grid (256 = b*64+y, 8 = g*2 + half32), 256 thr: pos=t&63 (pixel in row),
// sub=t>>6 -> 8 channels each. 288 scattered loads/thread; stores 128B
// coalesced per (k,ci). Bit-identical gather math to the fused version.
// ---------------------------------------------------------------------------
template<typename T>
__device__ __forceinline__ void dgather_body(const T* __restrict__ x,
    const float* __restrict__ offc, unsigned short* __restrict__ colsg){
  const int b = blockIdx.x >> 6, y = blockIdx.x & 63;
  const int s = blockIdx.y;
  const int g = s >> 1;
  const int c0 = (s & 1) * 32 + (threadIdx.x >> 6) * 8;  // channel base in group
  const int pos = threadIdx.x & 63;
  const int p = y * 64 + pos;
  const float* ob = offc + b * 18 * 4096 + p;
  const T* xg = x + ((b * 4 + g) * 64 + c0) * 4096;
  unsigned short* outb = colsg + ((b * 4 + g) * 576 + c0 * 9) * 4096 + p;
  #pragma unroll
  for (int k = 0; k < 9; k++){
    float dy = ob[(2 * k) * 4096];
    float dx = ob[(2 * k + 1) * 4096];
    float py = (float)(y + k / 3 - 1) + dy;
    float px = (float)(pos + k % 3 - 1) + dx;
    float y0f = floorf(py), x0f = floorf(px);
    int y0 = (int)y0f, x0 = (int)x0f;
    float wy1 = py - y0f, wx1 = px - x0f;
    float wy0 = 1.f - wy1, wx0 = 1.f - wx1;
    bool vy0 = (unsigned)y0 < 64u, vy1 = (unsigned)(y0 + 1) < 64u;
    bool vx0 = (unsigned)x0 < 64u, vx1 = (unsigned)(x0 + 1) < 64u;
    float w00 = (vy0 && vx0) ? wy0 * wx0 : 0.f;
    float w01 = (vy0 && vx1) ? wy0 * wx1 : 0.f;
    float w10 = (vy1 && vx0) ? wy1 * wx0 : 0.f;
    float w11 = (vy1 && vx1) ? wy1 * wx1 : 0.f;
    int yc0 = min(max(y0, 0), 63), yc1 = min(max(y0 + 1, 0), 63);
    int xc0 = min(max(x0, 0), 63), xc1 = min(max(x0 + 1, 0), 63);
    int i00 = yc0 * 64 + xc0, i01 = yc0 * 64 + xc1;
    int i10 = yc1 * 64 + xc0, i11 = yc1 * 64 + xc1;
    #pragma unroll
    for (int ci = 0; ci < 8; ci++){
      const T* xc = xg + ci * 4096;
      float val = w00 * ldv(xc, i00) + w01 * ldv(xc, i01)
                + w10 * ldv(xc, i10) + w11 * ldv(xc, i11);
      bf16 hv = __float2bfloat16(val);
      outb[(ci * 9 + k) * 4096] = *(unsigned short*)&hv;
    }
  }
}

__global__ __launch_bounds__(256) void k_dgather(const void* x, const int* flagp,
    const float* offc, unsigned short* colsg){
  if (*flagp) dgather_body((const float*)x, offc, colsg);
  else        dgather_body((const bf16*)x, offc, colsg);
}

// ---------------------------------------------------------------------------
// K2b: deform GEMM — xdir[b][g*64+co][p] = wdef[co][576] x colsg[b][g][k][p].
// grid (256 = b*64+y, 4 = g), 256 thr. 9 chunks of 64 k-rows staged to LDS
// (pitch 68 u16, uint2 copies — proven conflict-free read pattern). COT=4.
// Same ascending-k accumulation order as the fused kernel (bit-identical).
// ---------------------------------------------------------------------------
__global__ __launch_bounds__(256) void k_dmm(const unsigned short* __restrict__ colsg,
    const bf16* __restrict__ wdefb, float* __restrict__ xdir){
  __shared__ __align__(16) unsigned int lds[64 * 34];
  const int b = blockIdx.x >> 6, y = blockIdx.x & 63;
  const int g = blockIdx.y;
  const int t = threadIdx.x;
  const int l = t & 63, w = t >> 6;
  const int lm = l & 15, lq = l >> 4;
  const unsigned short* cbase = colsg + (b * 4 + g) * 576 * 4096 + y * 64;
  const unsigned short* l16 = (const unsigned short*)lds;
  f32x4 acc[4];
  #pragma unroll
  for (int m = 0; m < 4; m++) acc[m] = (f32x4){0.f,0.f,0.f,0.f};

  for (int kk0 = 0; kk0 < 576; kk0 += 64){
    __syncthreads();
    // stage 64 k-rows x 64 px (uint2 = 4 px per copy; 1024 uint2 total)
    #pragma unroll
    for (int it = 0; it < 4; it++){
      int idx = t + it * 256;
      int row = idx >> 4, q2 = idx & 15;
      uint2 v = *((const uint2*)(cbase + (kk0 + row) * 4096) + q2);
      *(uint2*)(lds + row * 34 + q2 * 2) = v;
    }
    __syncthreads();
    #pragma unroll
    for (int kk = 0; kk < 64; kk += 32){
      short8 bfr;
      #pragma unroll
      for (int j = 0; j < 8; j++)
        bfr[j] = (short)l16[(kk + lq * 8 + j) * 68 + w * 16 + lm];
      #pragma unroll
      for (int m = 0; m < 4; m++){
        const bf16* ap = wdefb + (g * 64 + m * 16 + lm) * 576 + kk0 + kk + lq * 8;
        short8 afr = *(const short8*)ap;
        acc[m] = __builtin_amdgcn_mfma_f32_16x16x32_bf16(afr, bfr, acc[m], 0, 0, 0);
      }
    }
  }
  const int pp = y * 64 + w * 16 + lm;
  #pragma unroll
  for (int m = 0; m < 4; m++){
    #pragma unroll
    for (int r = 0; r < 4; r++){
      const int co = g * 64 + m * 16 + lq * 4 + r;
      xdir[(b * 256 + co) * 4096 + pp] = acc[m][r];
    }
  }
}

// ---------------------------------------------------------------------------
// K3: 1x1 conv concat([x_dir, x_prev]) * w_cross (256x512) — MFMA.
// ---------------------------------------------------------------------------
template<typename T>
__device__ __forceinline__ void cross_mfma_body(const float* __restrict__ xdir,
    const T* __restrict__ xprev, const bf16* __restrict__ wb,
    float* __restrict__ xdense, unsigned short* cols){
  const int bx = blockIdx.x;
  const int b = bx >> 6, y = bx & 63;
  const int co0 = blockIdx.y * 128;
  const int t = threadIdx.x;
  const int l = t & 63, w = t >> 6;
  const int lm = l & 15, lq = l >> 4;
  const int pos2 = t & 31, cq = t >> 5;
  unsigned int* cols32 = (unsigned int*)cols;
  f32x4 acc[8];
  #pragma unroll
  for (int m = 0; m < 8; m++) acc[m] = (f32x4){0.f,0.f,0.f,0.f};

  for (int cc = 0; cc < 512; cc += 64){
    __syncthreads();
    #pragma unroll
    for (int c8 = 0; c8 < 8; c8++){
      const int cl = cq * 8 + c8;
      const int ci = cc + cl;
      float v0, v1;
      if (ci < 256){
        const float* row = xdir + (b * 256 + ci) * 4096 + y * 64 + 2 * pos2;
        v0 = row[0]; v1 = row[1];
      } else {
        const T* row = xprev + (b * 256 + (ci - 256)) * 4096 + y * 64 + 2 * pos2;
        v0 = ldv(row, 0); v1 = ldv(row, 1);
      }
      bf16 h0 = __float2bfloat16(v0), h1 = __float2bfloat16(v1);
      unsigned int packed = (unsigned int)*(unsigned short*)&h0
                          | ((unsigned int)*(unsigned short*)&h1 << 16);
      cols32[cl * 34 + pos2] = packed;
    }
    __syncthreads();
    #pragma unroll
    for (int kk = 0; kk < 64; kk += 32){
      short8 bfr;
      #pragma unroll
      for (int j = 0; j < 8; j++)
        bfr[j] = (short)cols[(kk + lq * 8 + j) * 68 + w * 16 + lm];
      #pragma unroll
      for (int m = 0; m < 8; m++){
        const bf16* ap = wb + (co0 + m * 16 + lm) * 512 + cc + kk + lq * 8;
        short8 afr = *(const short8*)ap;
        acc[m] = __builtin_amdgcn_mfma_f32_16x16x32_bf16(afr, bfr, acc[m], 0, 0, 0);
      }
    }
  }
  const int p = y * 64 + w * 16 + lm;
  #pragma unroll
  for (int m = 0; m < 8; m++){
    #pragma unroll
    for (int r = 0; r < 4; r++){
      const int co = co0 + m * 16 + lq * 4 + r;
      xdense[(b * 256 + co) * 4096 + p] = acc[m][r];
    }
  }
}

__global__ __launch_bounds__(256) void k_cross(const float* xdir, const void* xprev,
    const int* flagp, const bf16* wcb, float* xdense){
  __shared__ __align__(16) unsigned short cols[64 * 68];
  if (*flagp) cross_mfma_body(xdir, (const float*)xprev, wcb, xdense, cols);
  else        cross_mfma_body(xdir, (const bf16*)xprev, wcb, xdense, cols);
}

// ---------------------------------------------------------------------------
// K5: 1x1 conv 64->256 + bias + sigmoid, xa = xdense * attn. grid (64,64).
// ---------------------------------------------------------------------------
__global__ __launch_bounds__(256) void k_attn(
    const float* __restrict__ abuf, const float* __restrict__ cw,
    const float* __restrict__ cb, const float* __restrict__ xdense,
    float* __restrict__ xa){
  const int q0 = blockIdx.x * 256;
  const int b = q0 >> 12, p0 = q0 & 4095;
  const int co0 = blockIdx.y * 4;
  const int p = p0 + threadIdx.x;
  float acc[4] = {0,0,0,0};
  const float* ab = abuf + b * 64 * 4096;
  for (int c = 0; c < 64; c++){
    float av = ab[c * 4096 + p];
    acc[0] += cw[(co0 + 0) * 64 + c] * av;
    acc[1] += cw[(co0 + 1) * 64 + c] * av;
    acc[2] += cw[(co0 + 2) * 64 + c] * av;
    acc[3] += cw[(co0 + 3) * 64 + c] * av;
  }
  #pragma unroll
  for (int j = 0; j < 4; j++){
    int co = co0 + j;
    float attn = sigf(acc[j] + cb[co]);
    int idx = (b * 256 + co) * 4096 + p;
    xa[idx] = xdense[idx] * attn;
  }
}

// ---------------------------------------------------------------------------
// K6: 1x1 conv 256->256 + bias + BN + SiLU + residual — MFMA.
// ---------------------------------------------------------------------------
template<typename T>
__device__ __forceinline__ void out_mfma_body(const float* __restrict__ xa,
    const bf16* __restrict__ wb, const float* __restrict__ cbv,
    const float* __restrict__ gam, const float* __restrict__ bet,
    const float* __restrict__ mea, const float* __restrict__ var,
    const T* __restrict__ xres, T* __restrict__ outp, unsigned short* cols){
  const int bx = blockIdx.x;
  const int b = bx >> 6, y = bx & 63;
  const int co0 = blockIdx.y * 128;
  const int t = threadIdx.x;
  const int l = t & 63, w = t >> 6;
  const int lm = l & 15, lq = l >> 4;
  const int pos2 = t & 31, cq = t >> 5;
  unsigned int* cols32 = (unsigned int*)cols;
  f32x4 acc[8];
  #pragma unroll
  for (int m = 0; m < 8; m++) acc[m] = (f32x4){0.f,0.f,0.f,0.f};

  for (int cc = 0; cc < 256; cc += 64){
    __syncthreads();
    #pragma unroll
    for (int c8 = 0; c8 < 8; c8++){
      const int cl = cq * 8 + c8;
      const int ci = cc + cl;
      const float* row = xa + (b * 256 + ci) * 4096 + y * 64 + 2 * pos2;
      float v0 = row[0], v1 = row[1];
      bf16 h0 = __float2bfloat16(v0), h1 = __float2bfloat16(v1);
      unsigned int packed = (unsigned int)*(unsigned short*)&h0
                          | ((unsigned int)*(unsigned short*)&h1 << 16);
      cols32[cl * 34 + pos2] = packed;
    }
    __syncthreads();
    #pragma unroll
    for (int kk = 0; kk < 64; kk += 32){
      short8 bfr;
      #pragma unroll
      for (int j = 0; j < 8; j++)
        bfr[j] = (short)cols[(kk + lq * 8 + j) * 68 + w * 16 + lm];
      #pragma unroll
      for (int m = 0; m < 8; m++){
        const bf16* ap = wb + (co0 + m * 16 + lm) * 256 + cc + kk + lq * 8;
        short8 afr = *(const short8*)ap;
        acc[m] = __builtin_amdgcn_mfma_f32_16x16x32_bf16(afr, bfr, acc[m], 0, 0, 0);
      }
    }
  }
  const int p = y * 64 + w * 16 + lm;
  #pragma unroll
  for (int m = 0; m < 8; m++){
    #pragma unroll
    for (int r = 0; r < 4; r++){
      const int co = co0 + m * 16 + lq * 4 + r;
      float inv = gam[co] * rsqrtf(var[co] + 1e-5f);
      float v = acc[m][r] + cbv[co];
      v = v * inv + (bet[co] - mea[co] * inv);
      v = v * sigf(v);
      const int idx = (b * 256 + co) * 4096 + p;
      stv(outp, idx, v + ldv(xres, idx));
    }
  }
}

__global__ __launch_bounds__(256) void k_out(const float* xa, const bf16* wob,
    const float* cb, const float* gam, const float* bet, const float* mea,
    const float* var, const void* xres, void* out, const int* flagp){
  __shared__ __align__(16) unsigned short cols[64 * 68];
  if (*flagp) out_mfma_body(xa, wob, cb, gam, bet, mea, var,
                            (const float*)xres, (float*)out, cols);
  else        out_mfma_body(xa, wob, cb, gam, bet, mea, var,
                            (const bf16*)xres, (bf16*)out, cols);
}

// ---------------------------------------------------------------------------
extern "C" void kernel_launch(void* const* d_in, const int* in_sizes, int n_in,
                              void* d_out, int out_size, void* d_ws, size_t ws_size,
                              hipStream_t stream) {
  const void* x      = d_in[0];
  const void* x_prev = d_in[1];

  float* ws   = (float*)d_ws;
  int*   flag = (int*)ws;                 // ws[0..15] reserved
  float* cpar = ws + 16;                  // canonical fp32 params (551264 f)
  float* cb_off   = cpar + 41472;
  float* cb_g1    = cpar + 467488;
  float* cg1_gam  = cpar + 467552;
  float* cg1_bet  = cpar + 467616;
  float* cg1_mea  = cpar + 467680;
  float* cg1_var  = cpar + 467744;
  float* cw_g2    = cpar + 467808;
  float* cb_g2    = cpar + 484192;
  float* cb_out   = cpar + 549984;
  float* co_gam   = cpar + 550240;
  float* co_bet   = cpar + 550496;
  float* co_mea   = cpar + 550752;
  float* co_var   = cpar + 551008;

  bf16*  wdefb   = (bf16*)(ws + 551280);            // 147456 hw = 73728 f
  bf16*  woffb   = (bf16*)(ws + 625008);            // 73728 hw  = 36864 f
  bf16*  wg1b    = (bf16*)(ws + 661872);            // 147456 hw = 73728 f
  bf16*  wcrossb = (bf16*)(ws + 735600);            // 131072 hw = 65536 f
  bf16*  woutb   = (bf16*)(ws + 801136);            //  65536 hw = 32768 f
  float* base    = ws + 833904;
  float* offc   = base;                   // 4*18*4096  = 294912 f
  float* xdir   = offc + 294912;          // 4*256*4096 = 4194304 f
  float* xdense = xdir + 4194304;         // 4194304 f
  float* abuf   = xdense + 4194304;       // 1048576 f
  float* xa     = xdir;                   // reuse (xdir dead after K3)
  unsigned short* colsg = (unsigned short*)(abuf + 1048576); // 4*4*576*4096 u16 = 75.5MB

  ParamSrc ps;
  for (int i = 0; i < 18; i++) ps.p[i] = d_in[2 + i];

  k_detect<<<dim3(1), 256, 0, stream>>>((const unsigned short*)x, flag);
  k_convert<<<dim3(96, 23), 256, 0, stream>>>(ps, flag, cpar, wdefb, woffb,
                                              wg1b, wcrossb, woutb);
  k_coff_m<<<dim3(256), 256, 0, stream>>>(x, flag, woffb, cb_off, offc);
  k_dgather<<<dim3(256, 8), 256, 0, stream>>>(x, flag, offc, colsg);
  k_dmm<<<dim3(256, 4), 256, 0, stream>>>(colsg, wdefb, xdir);
  k_cross<<<dim3(256, 2), 256, 0, stream>>>(xdir, x_prev, flag, wcrossb, xdense);
  k_g1_m<<<dim3(256), 256, 0, stream>>>(xdense, wg1b, cb_g1, cg1_gam, cg1_bet,
                                        cg1_mea, cg1_var, abuf);
  k_attn<<<dim3(64, 64), 256, 0, stream>>>(abuf, cw_g2, cb_g2, xdense, xa);
  k_out<<<dim3(256, 2), 256, 0, stream>>>(xa, woutb, cb_out, co_gam, co_bet,
                                          co_mea, co_var, x, d_out, flag);
}

// Round 6
// 469.715 us; speedup vs baseline: 1.1501x; 1.1501x over previous
//
#include <hip/hip_runtime.h>
#include <hip/hip_bf16.h>

using bf16 = __hip_bfloat16;
typedef __attribute__((ext_vector_type(8))) short short8;
typedef __attribute__((ext_vector_type(4))) float f32x4;

__device__ __forceinline__ float b2f(bf16 v){ return __bfloat162float(v); }
__device__ __forceinline__ float sigf(float v){ return 1.f/(1.f + __expf(-v)); }
__device__ __forceinline__ float ldv(const float* p, int i){ return p[i]; }
__device__ __forceinline__ float ldv(const bf16* p, int i){ return b2f(p[i]); }
__device__ __forceinline__ void stv(float* p, int i, float v){ p[i] = v; }
__device__ __forceinline__ void stv(bf16* p, int i, float v){ p[i] = __float2bfloat16(v); }

// ---------------------------------------------------------------------------
// K0: dtype detect. flag=1 => inputs are f32.
// ---------------------------------------------------------------------------
__global__ __launch_bounds__(256) void k_detect(const unsigned short* xs, int* flag){
  __shared__ int cnt;
  if (threadIdx.x == 0) cnt = 0;
  __syncthreads();
  int local = 0;
  for (int i = threadIdx.x; i < 16384; i += 256){
    if (((xs[i] >> 7) & 0xFF) == 0xFF) local++;
  }
  if (local) atomicAdd(&cnt, local);
  __syncthreads();
  if (threadIdx.x == 0) *flag = (cnt > 0) ? 1 : 0;
}

// ---------------------------------------------------------------------------
// K0b: canonicalize params. slots 0-17: fp32 in cpar; 18: w_def->bf16;
// 19: w_off->bf16 padded 18->32 rows; 20: w_g1->bf16; 21: w_cross->bf16;
// 22: w_out->bf16. grid (96, 23).
// ---------------------------------------------------------------------------
struct ParamSrc { const void* p[18]; };

__global__ __launch_bounds__(256) void k_convert(ParamSrc ps, const int* flagp,
    float* cpar, bf16* wdefb, bf16* woffb, bf16* wg1b, bf16* wcrossb, bf16* woutb){
  static constexpr int n[23]   = {41472,18,147456,131072,147456,64,64,64,64,64,
                                  16384,256,65536,256,256,256,256,256,
                                  147456,73728,147456,131072,65536};
  static constexpr int off[18] = {0,41472,41504,188960,320032,467488,467552,467616,
                                  467680,467744,467808,484192,484448,549984,550240,
                                  550496,550752,551008};
  const int s = blockIdx.y;
  const bool f32 = (*flagp != 0);
  if (s >= 18){
    static constexpr int srcs[5] = {2, 0, 4, 3, 12};
    const int src_slot = srcs[s - 18];
    bf16* dst = (s == 18) ? wdefb : (s == 19) ? woffb : (s == 20) ? wg1b
              : (s == 21) ? wcrossb : woutb;
    const int nsrc = (s == 19) ? 41472 : n[s];
    if (f32){
      const float* src = (const float*)ps.p[src_slot];
      for (int i = blockIdx.x * 256 + threadIdx.x; i < n[s]; i += gridDim.x * 256)
        dst[i] = (i < nsrc) ? __float2bfloat16(src[i]) : __float2bfloat16(0.f);
    } else {
      const bf16* src = (const bf16*)ps.p[src_slot];
      for (int i = blockIdx.x * 256 + threadIdx.x; i < n[s]; i += gridDim.x * 256)
        dst[i] = (i < nsrc) ? src[i] : __float2bfloat16(0.f);
    }
    return;
  }
  float* dst = cpar + off[s];
  if (f32){
    const float* src = (const float*)ps.p[s];
    for (int i = blockIdx.x * 256 + threadIdx.x; i < n[s]; i += gridDim.x * 256)
      dst[i] = src[i];
  } else {
    const bf16* src = (const bf16*)ps.p[s];
    for (int i = blockIdx.x * 256 + threadIdx.x; i < n[s]; i += gridDim.x * 256)
      dst[i] = b2f(src[i]);
  }
}

// ---------------------------------------------------------------------------
// K1b: NHWC staging for deform gather. x_t[b][g][p=4096][cg=64] f32.
// grid 1024: bx -> b (4) | y (64) | cc-quarter (4). Block: LDS 64x65 f32
// transpose tile. Loads coalesced along px; stores coalesced along ch.
// ---------------------------------------------------------------------------
template<typename T>
__device__ __forceinline__ void xt_body(const T* __restrict__ x, float* __restrict__ xt){
  __shared__ float lds[64][65];
  const int bx = blockIdx.x;
  const int b = bx >> 8, y = (bx >> 2) & 63, g = bx & 3;
  const int t = threadIdx.x;
  const int px = t & 63, cq = t >> 6;            // load ids
  #pragma unroll
  for (int it = 0; it < 16; it++){
    const int ch = cq * 16 + it;
    lds[ch][px] = ldv(x, ((b * 256 + g * 64 + ch) * 64 + y) * 64 + px);
  }
  __syncthreads();
  const int ch = t & 63, pb = t >> 6;            // store ids
  float* ob = xt + ((b * 4 + g) * 4096 + y * 64) * 64 + ch;
  #pragma unroll
  for (int i = 0; i < 16; i++){
    const int p = pb * 16 + i;
    ob[p * 64] = lds[ch][p];
  }
}

__global__ __launch_bounds__(256) void k_xt(const void* x, const int* flagp, float* xt){
  if (*flagp) xt_body((const float*)x, xt);
  else        xt_body((const bf16*)x, xt);
}

// ---------------------------------------------------------------------------
// Generic 3x3 pad=1 conv via im2col + MFMA (k_coff_m / k_g1_m) — unchanged.
// ---------------------------------------------------------------------------
template<typename T, int COT, bool EPI>
__device__ __forceinline__ void conv3_body(const T* __restrict__ xin,
    const bf16* __restrict__ wb, const float* __restrict__ cbv,
    const float* __restrict__ gam, const float* __restrict__ bet,
    const float* __restrict__ mea, const float* __restrict__ var,
    float* __restrict__ outp, int co_lim, unsigned short* cols){
  const int bx = blockIdx.x;
  const int b = bx >> 6, y = bx & 63;
  const int t = threadIdx.x;
  const int l = t & 63, w = t >> 6;
  const int lm = l & 15, lq = l >> 4;
  const int pos2 = t & 31, kq = t >> 5;
  unsigned int* cols32 = (unsigned int*)cols;
  f32x4 acc[COT];
  #pragma unroll
  for (int m = 0; m < COT; m++) acc[m] = (f32x4){0.f,0.f,0.f,0.f};

  for (int cc = 0; cc < 256; cc += 32){
    __syncthreads();
    #pragma unroll
    for (int c8 = 0; c8 < 4; c8++){
      const int c_local = kq * 4 + c8;
      const T* xc = xin + (b * 256 + cc + c_local) * 4096;
      #pragma unroll
      for (int tap = 0; tap < 9; tap++){
        const int ti = tap / 3, tj = tap % 3;
        const int yy = y + ti - 1;
        const int px0 = 2 * pos2 + tj - 1;
        const bool vy = (unsigned)yy < 64u;
        float v0 = (vy && (unsigned)px0 < 64u) ? ldv(xc, yy * 64 + px0) : 0.f;
        float v1 = (vy && (unsigned)(px0 + 1) < 64u) ? ldv(xc, yy * 64 + px0 + 1) : 0.f;
        bf16 h0 = __float2bfloat16(v0), h1 = __float2bfloat16(v1);
        unsigned int packed = (unsigned int)*(unsigned short*)&h0
                            | ((unsigned int)*(unsigned short*)&h1 << 16);
        cols32[(c_local * 9 + tap) * 34 + pos2] = packed;
      }
    }
    __syncthreads();
    #pragma unroll
    for (int kk = 0; kk < 288; kk += 32){
      short8 bfr;
      #pragma unroll
      for (int j = 0; j < 8; j++)
        bfr[j] = (short)cols[(kk + lq * 8 + j) * 68 + w * 16 + lm];
      #pragma unroll
      for (int m = 0; m < COT; m++){
        const bf16* ap = wb + (m * 16 + lm) * 2304 + cc * 9 + kk + lq * 8;
        short8 afr = *(const short8*)ap;
        acc[m] = __builtin_amdgcn_mfma_f32_16x16x32_bf16(afr, bfr, acc[m], 0, 0, 0);
      }
    }
  }
  const int p = y * 64 + w * 16 + lm;
  #pragma unroll
  for (int m = 0; m < COT; m++){
    #pragma unroll
    for (int r = 0; r < 4; r++){
      const int co = m * 16 + lq * 4 + r;
      if (co >= co_lim) continue;
      float v = acc[m][r] + cbv[co];
      if constexpr (EPI){
        float inv = gam[co] * rsqrtf(var[co] + 1e-5f);
        v = v * inv + (bet[co] - mea[co] * inv);
        v = v * sigf(v);
      }
      outp[(b * co_lim + co) * 4096 + p] = v;
    }
  }
}

__global__ __launch_bounds__(256) void k_coff_m(const void* x, const int* flagp,
    const bf16* woffb, const float* cb, float* offc){
  __shared__ __align__(16) unsigned short cols[288 * 68];
  if (*flagp) conv3_body<float, 2, false>((const float*)x, woffb, cb,
                  nullptr, nullptr, nullptr, nullptr, offc, 18, cols);
  else        conv3_body<bf16, 2, false>((const bf16*)x, woffb, cb,
                  nullptr, nullptr, nullptr, nullptr, offc, 18, cols);
}

__global__ __launch_bounds__(256) void k_g1_m(const float* xdense,
    const bf16* wg1b, const float* cb, const float* gam, const float* bet,
    const float* mea, const float* var, float* abuf){
  __shared__ __align__(16) unsigned short cols[288 * 68];
  conv3_body<float, 4, true>(xdense, wg1b, cb, gam, bet, mea, var, abuf, 64, cols);
}

// ---------------------------------------------------------------------------
// K2: deformable conv, MFMA, fused, K split into 2 halves of 288 (R3
// structure). R5 change: gather reads NHWC f32 x_t — each corner is a
// float4 (4 ch / 16 B), 4 loads per (thread,tap) instead of 32 scalar
// channel-strided loads. Same FMA expression / rounding point / k-order
// as the passing fused kernel => bit-identical output.
// ---------------------------------------------------------------------------
#define CROW2 292

__global__ __launch_bounds__(256) void k_deform(const float* __restrict__ xt,
    const float* __restrict__ offc, const bf16* __restrict__ wdefb,
    float* __restrict__ xdir){
  __shared__ __align__(16) unsigned short cols[32 * CROW2];
  const int g = blockIdx.y;
  const int q0 = blockIdx.x * 32;
  const int b = q0 >> 12, p0 = q0 & 4095;
  const int t = threadIdx.x;
  // gather ids: 32 pos x 8 units; each unit covers 4 channels of the half
  const int pos = t & 31, u4 = t >> 5;
  const int c0 = u4 * 4;
  const int p = p0 + pos;
  const int y = p >> 6, xx = p & 63;
  const float* ob = offc + b * 18 * 4096 + p;
  const float* xg = xt + (b * 4 + g) * 4096 * 64;   // [pixel][64ch]
  // MFMA ids
  const int w = t >> 6;
  const int l = t & 63;
  const int lrow = l & 15;
  const int lhi = l >> 4;
  f32x4 acc0 = {0.f, 0.f, 0.f, 0.f};
  f32x4 acc1 = {0.f, 0.f, 0.f, 0.f};
  const bf16* wr = wdefb + (g * 64 + w * 16 + lrow) * 576;
  const unsigned short* b0p = cols + lrow * CROW2;
  const unsigned short* b1p = cols + (16 + lrow) * CROW2;

  #pragma unroll
  for (int half = 0; half < 2; half++){
    __syncthreads();   // cols free (previous half's MFMA done)
    const int hb = half * 32 + c0;   // channel offset within [64ch]
    #pragma unroll
    for (int k = 0; k < 9; k++){
      float dy = ob[(2 * k) * 4096];
      float dx = ob[(2 * k + 1) * 4096];
      float py = (float)(y + k / 3 - 1) + dy;
      float px = (float)(xx + k % 3 - 1) + dx;
      float y0f = floorf(py), x0f = floorf(px);
      int y0 = (int)y0f, x0 = (int)x0f;
      float wy1 = py - y0f, wx1 = px - x0f;
      float wy0 = 1.f - wy1, wx0 = 1.f - wx1;
      bool vy0 = (unsigned)y0 < 64u, vy1 = (unsigned)(y0 + 1) < 64u;
      bool vx0 = (unsigned)x0 < 64u, vx1 = (unsigned)(x0 + 1) < 64u;
      float w00 = (vy0 && vx0) ? wy0 * wx0 : 0.f;
      float w01 = (vy0 && vx1) ? wy0 * wx1 : 0.f;
      float w10 = (vy1 && vx0) ? wy1 * wx0 : 0.f;
      float w11 = (vy1 && vx1) ? wy1 * wx1 : 0.f;
      int yc0 = min(max(y0, 0), 63), yc1 = min(max(y0 + 1, 0), 63);
      int xc0 = min(max(x0, 0), 63), xc1 = min(max(x0 + 1, 0), 63);
      int i00 = yc0 * 64 + xc0, i01 = yc0 * 64 + xc1;
      int i10 = yc1 * 64 + xc0, i11 = yc1 * 64 + xc1;
      f32x4 v00 = *(const f32x4*)(xg + i00 * 64 + hb);
      f32x4 v01 = *(const f32x4*)(xg + i01 * 64 + hb);
      f32x4 v10 = *(const f32x4*)(xg + i10 * 64 + hb);
      f32x4 v11 = *(const f32x4*)(xg + i11 * 64 + hb);
      #pragma unroll
      for (int j = 0; j < 4; j++){
        float val = w00 * v00[j] + w01 * v01[j]
                  + w10 * v10[j] + w11 * v11[j];
        bf16 hv = __float2bfloat16(val);
        cols[pos * CROW2 + (c0 + j) * 9 + k] = *(unsigned short*)&hv;
      }
    }
    __syncthreads();
    const int kbase = half * 288;
    #pragma unroll 2
    for (int kk = 0; kk < 288; kk += 32){
      int ko = kk + lhi * 8;
      short8 a  = *(const short8*)(wr + kbase + ko);
      short8 b0 = *(const short8*)(b0p + ko);
      short8 b1 = *(const short8*)(b1p + ko);
      acc0 = __builtin_amdgcn_mfma_f32_16x16x32_bf16(a, b0, acc0, 0, 0, 0);
      acc1 = __builtin_amdgcn_mfma_f32_16x16x32_bf16(a, b1, acc1, 0, 0, 0);
    }
  }
  const int co_base = g * 64 + w * 16 + lhi * 4;
  #pragma unroll
  for (int r = 0; r < 4; r++){
    float* xo = xdir + (b * 256 + co_base + r) * 4096 + p0 + lrow;
    xo[0]  = acc0[r];
    xo[16] = acc1[r];
  }
}

// ---------------------------------------------------------------------------
// K3: 1x1 conv concat([x_dir, x_prev]) * w_cross (256x512) — MFMA.
// ---------------------------------------------------------------------------
template<typename T>
__device__ __forceinline__ void cross_mfma_body(const float* __restrict__ xdir,
    const T* __restrict__ xprev, const bf16* __restrict__ wb,
    float* __restrict__ xdense, unsigned short* cols){
  const int bx = blockIdx.x;
  const int b = bx >> 6, y = bx & 63;
  const int co0 = blockIdx.y * 128;
  const int t = threadIdx.x;
  const int l = t & 63, w = t >> 6;
  const int lm = l & 15, lq = l >> 4;
  const int pos2 = t & 31, cq = t >> 5;
  unsigned int* cols32 = (unsigned int*)cols;
  f32x4 acc[8];
  #pragma unroll
  for (int m = 0; m < 8; m++) acc[m] = (f32x4){0.f,0.f,0.f,0.f};

  for (int cc = 0; cc < 512; cc += 64){
    __syncthreads();
    #pragma unroll
    for (int c8 = 0; c8 < 8; c8++){
      const int cl = cq * 8 + c8;
      const int ci = cc + cl;
      float v0, v1;
      if (ci < 256){
        const float* row = xdir + (b * 256 + ci) * 4096 + y * 64 + 2 * pos2;
        v0 = row[0]; v1 = row[1];
      } else {
        const T* row = xprev + (b * 256 + (ci - 256)) * 4096 + y * 64 + 2 * pos2;
        v0 = ldv(row, 0); v1 = ldv(row, 1);
      }
      bf16 h0 = __float2bfloat16(v0), h1 = __float2bfloat16(v1);
      unsigned int packed = (unsigned int)*(unsigned short*)&h0
                          | ((unsigned int)*(unsigned short*)&h1 << 16);
      cols32[cl * 34 + pos2] = packed;
    }
    __syncthreads();
    #pragma unroll
    for (int kk = 0; kk < 64; kk += 32){
      short8 bfr;
      #pragma unroll
      for (int j = 0; j < 8; j++)
        bfr[j] = (short)cols[(kk + lq * 8 + j) * 68 + w * 16 + lm];
      #pragma unroll
      for (int m = 0; m < 8; m++){
        const bf16* ap = wb + (co0 + m * 16 + lm) * 512 + cc + kk + lq * 8;
        short8 afr = *(const short8*)ap;
        acc[m] = __builtin_amdgcn_mfma_f32_16x16x32_bf16(afr, bfr, acc[m], 0, 0, 0);
      }
    }
  }
  const int p = y * 64 + w * 16 + lm;
  #pragma unroll
  for (int m = 0; m < 8; m++){
    #pragma unroll
    for (int r = 0; r < 4; r++){
      const int co = co0 + m * 16 + lq * 4 + r;
      xdense[(b * 256 + co) * 4096 + p] = acc[m][r];
    }
  }
}

__global__ __launch_bounds__(256) void k_cross(const float* xdir, const void* xprev,
    const int* flagp, const bf16* wcb, float* xdense){
  __shared__ __align__(16) unsigned short cols[64 * 68];
  if (*flagp) cross_mfma_body(xdir, (const float*)xprev, wcb, xdense, cols);
  else        cross_mfma_body(xdir, (const bf16*)xprev, wcb, xdense, cols);
}

// ---------------------------------------------------------------------------
// K5: 1x1 conv 64->256 + bias + sigmoid, xa = xdense * attn. grid (64,64).
// ---------------------------------------------------------------------------
__global__ __launch_bounds__(256) void k_attn(
    const float* __restrict__ abuf, const float* __restrict__ cw,
    const float* __restrict__ cb, const float* __restrict__ xdense,
    float* __restrict__ xa){
  const int q0 = blockIdx.x * 256;
  const int b = q0 >> 12, p0 = q0 & 4095;
  const int co0 = blockIdx.y * 4;
  const int p = p0 + threadIdx.x;
  float acc[4] = {0,0,0,0};
  const float* ab = abuf + b * 64 * 4096;
  for (int c = 0; c < 64; c++){
    float av = ab[c * 4096 + p];
    acc[0] += cw[(co0 + 0) * 64 + c] * av;
    acc[1] += cw[(co0 + 1) * 64 + c] * av;
    acc[2] += cw[(co0 + 2) * 64 + c] * av;
    acc[3] += cw[(co0 + 3) * 64 + c] * av;
  }
  #pragma unroll
  for (int j = 0; j < 4; j++){
    int co = co0 + j;
    float attn = sigf(acc[j] + cb[co]);
    int idx = (b * 256 + co) * 4096 + p;
    xa[idx] = xdense[idx] * attn;
  }
}

// ---------------------------------------------------------------------------
// K6: 1x1 conv 256->256 + bias + BN + SiLU + residual — MFMA.
// ---------------------------------------------------------------------------
template<typename T>
__device__ __forceinline__ void out_mfma_body(const float* __restrict__ xa,
    const bf16* __restrict__ wb, const float* __restrict__ cbv,
    const float* __restrict__ gam, const float* __restrict__ bet,
    const float* __restrict__ mea, const float* __restrict__ var,
    const T* __restrict__ xres, T* __restrict__ outp, unsigned short* cols){
  const int bx = blockIdx.x;
  const int b = bx >> 6, y = bx & 63;
  const int co0 = blockIdx.y * 128;
  const int t = threadIdx.x;
  const int l = t & 63, w = t >> 6;
  const int lm = l & 15, lq = l >> 4;
  const int pos2 = t & 31, cq = t >> 5;
  unsigned int* cols32 = (unsigned int*)cols;
  f32x4 acc[8];
  #pragma unroll
  for (int m = 0; m < 8; m++) acc[m] = (f32x4){0.f,0.f,0.f,0.f};

  for (int cc = 0; cc < 256; cc += 64){
    __syncthreads();
    #pragma unroll
    for (int c8 = 0; c8 < 8; c8++){
      const int cl = cq * 8 + c8;
      const int ci = cc + cl;
      const float* row = xa + (b * 256 + ci) * 4096 + y * 64 + 2 * pos2;
      float v0 = row[0], v1 = row[1];
      bf16 h0 = __float2bfloat16(v0), h1 = __float2bfloat16(v1);
      unsigned int packed = (unsigned int)*(unsigned short*)&h0
                          | ((unsigned int)*(unsigned short*)&h1 << 16);
      cols32[cl * 34 + pos2] = packed;
    }
    __syncthreads();
    #pragma unroll
    for (int kk = 0; kk < 64; kk += 32){
      short8 bfr;
      #pragma unroll
      for (int j = 0; j < 8; j++)
        bfr[j] = (short)cols[(kk + lq * 8 + j) * 68 + w * 16 + lm];
      #pragma unroll
      for (int m = 0; m < 8; m++){
        const bf16* ap = wb + (co0 + m * 16 + lm) * 256 + cc + kk + lq * 8;
        short8 afr = *(const short8*)ap;
        acc[m] = __builtin_amdgcn_mfma_f32_16x16x32_bf16(afr, bfr, acc[m], 0, 0, 0);
      }
    }
  }
  const int p = y * 64 + w * 16 + lm;
  #pragma unroll
  for (int m = 0; m < 8; m++){
    #pragma unroll
    for (int r = 0; r < 4; r++){
      const int co = co0 + m * 16 + lq * 4 + r;
      float inv = gam[co] * rsqrtf(var[co] + 1e-5f);
      float v = acc[m][r] + cbv[co];
      v = v * inv + (bet[co] - mea[co] * inv);
      v = v * sigf(v);
      const int idx = (b * 256 + co) * 4096 + p;
      stv(outp, idx, v + ldv(xres, idx));
    }
  }
}

__global__ __launch_bounds__(256) void k_out(const float* xa, const bf16* wob,
    const float* cb, const float* gam, const float* bet, const float* mea,
    const float* var, const void* xres, void* out, const int* flagp){
  __shared__ __align__(16) unsigned short cols[64 * 68];
  if (*flagp) out_mfma_body(xa, wob, cb, gam, bet, mea, var,
                            (const float*)xres, (float*)out, cols);
  else        out_mfma_body(xa, wob, cb, gam, bet, mea, var,
                            (const bf16*)xres, (bf16*)out, cols);
}

// ---------------------------------------------------------------------------
extern "C" void kernel_launch(void* const* d_in, const int* in_sizes, int n_in,
                              void* d_out, int out_size, void* d_ws, size_t ws_size,
                              hipStream_t stream) {
  const void* x      = d_in[0];
  const void* x_prev = d_in[1];

  float* ws   = (float*)d_ws;
  int*   flag = (int*)ws;                 // ws[0..15] reserved
  float* cpar = ws + 16;                  // canonical fp32 params (551264 f)
  float* cb_off   = cpar + 41472;
  float* cb_g1    = cpar + 467488;
  float* cg1_gam  = cpar + 467552;
  float* cg1_bet  = cpar + 467616;
  float* cg1_mea  = cpar + 467680;
  float* cg1_var  = cpar + 467744;
  float* cw_g2    = cpar + 467808;
  float* cb_g2    = cpar + 484192;
  float* cb_out   = cpar + 549984;
  float* co_gam   = cpar + 550240;
  float* co_bet   = cpar + 550496;
  float* co_mea   = cpar + 550752;
  float* co_var   = cpar + 551008;

  bf16*  wdefb   = (bf16*)(ws + 551280);            // 147456 hw = 73728 f
  bf16*  woffb   = (bf16*)(ws + 625008);            // 73728 hw  = 36864 f
  bf16*  wg1b    = (bf16*)(ws + 661872);            // 147456 hw = 73728 f
  bf16*  wcrossb = (bf16*)(ws + 735600);            // 131072 hw = 65536 f
  bf16*  woutb   = (bf16*)(ws + 801136);            //  65536 hw = 32768 f
  float* base    = ws + 833904;
  float* offc   = base;                   // 4*18*4096  = 294912 f
  float* xdir   = offc + 294912;          // 4*256*4096 = 4194304 f
  float* xdense = xdir + 4194304;         // 4194304 f
  float* abuf   = xdense + 4194304;       // 1048576 f
  float* xt     = abuf + 1048576;         // 4*4*4096*64 = 4194304 f (NHWC)
  float* xa     = xdir;                   // reuse (xdir dead after K3)

  ParamSrc ps;
  for (int i = 0; i < 18; i++) ps.p[i] = d_in[2 + i];

  k_detect<<<dim3(1), 256, 0, stream>>>((const unsigned short*)x, flag);
  k_convert<<<dim3(96, 23), 256, 0, stream>>>(ps, flag, cpar, wdefb, woffb,
                                              wg1b, wcrossb, woutb);
  k_xt<<<dim3(1024), 256, 0, stream>>>(x, flag, xt);
  k_coff_m<<<dim3(256), 256, 0, stream>>>(x, flag, woffb, cb_off, offc);
  k_deform<<<dim3(512, 4), 256, 0, stream>>>(xt, offc, wdefb, xdir);
  k_cross<<<dim3(256, 2), 256, 0, stream>>>(xdir, x_prev, flag, wcrossb, xdense);
  k_g1_m<<<dim3(256), 256, 0, stream>>>(xdense, wg1b, cb_g1, cg1_gam, cg1_bet,
                                        cg1_mea, cg1_var, abuf);
  k_attn<<<dim3(64, 64), 256, 0, stream>>>(abuf, cw_g2, cb_g2, xdense, xa);
  k_out<<<dim3(256, 2), 256, 0, stream>>>(xa, woutb, cb_out, co_gam, co_bet,
                                          co_mea, co_var, x, d_out, flag);
}

// Round 8
// 424.953 us; speedup vs baseline: 1.2713x; 1.1053x over previous
//
#include <hip/hip_runtime.h>
#include <hip/hip_bf16.h>

using bf16 = __hip_bfloat16;
typedef __attribute__((ext_vector_type(8))) short short8;
typedef __attribute__((ext_vector_type(4))) float f32x4;

__device__ __forceinline__ float b2f(bf16 v){ return __bfloat162float(v); }
__device__ __forceinline__ float sigf(float v){ return 1.f/(1.f + __expf(-v)); }
__device__ __forceinline__ float ldv(const float* p, int i){ return p[i]; }
__device__ __forceinline__ float ldv(const bf16* p, int i){ return b2f(p[i]); }
__device__ __forceinline__ void stv(float* p, int i, float v){ p[i] = v; }
__device__ __forceinline__ void stv(bf16* p, int i, float v){ p[i] = __float2bfloat16(v); }

// ---------------------------------------------------------------------------
// K0: dtype detect. flag=1 => inputs are f32.
// ---------------------------------------------------------------------------
__global__ __launch_bounds__(256) void k_detect(const unsigned short* xs, int* flag){
  __shared__ int cnt;
  if (threadIdx.x == 0) cnt = 0;
  __syncthreads();
  int local = 0;
  for (int i = threadIdx.x; i < 16384; i += 256){
    if (((xs[i] >> 7) & 0xFF) == 0xFF) local++;
  }
  if (local) atomicAdd(&cnt, local);
  __syncthreads();
  if (threadIdx.x == 0) *flag = (cnt > 0) ? 1 : 0;
}

// ---------------------------------------------------------------------------
// K0b: canonicalize params. slots 0-17: fp32 in cpar; 18-22: bf16 weights;
// 23: w_g2 (input slot 10!) transposed fp32 cwT[c][co]. grid (96, 24).
// ---------------------------------------------------------------------------
struct ParamSrc { const void* p[18]; };

__global__ __launch_bounds__(256) void k_convert(ParamSrc ps, const int* flagp,
    float* cpar, bf16* wdefb, bf16* woffb, bf16* wg1b, bf16* wcrossb, bf16* woutb,
    float* cwT){
  static constexpr int n[24]   = {41472,18,147456,131072,147456,64,64,64,64,64,
                                  16384,256,65536,256,256,256,256,256,
                                  147456,73728,147456,131072,65536,16384};
  static constexpr int off[18] = {0,41472,41504,188960,320032,467488,467552,467616,
                                  467680,467744,467808,484192,484448,549984,550240,
                                  550496,550752,551008};
  const int s = blockIdx.y;
  const bool f32 = (*flagp != 0);
  if (s == 23){
    // w_g2 is input slot 10: [256 co][64 c] -> cwT [64 c][256 co]
    for (int i = blockIdx.x * 256 + threadIdx.x; i < 16384; i += gridDim.x * 256){
      const int c = i >> 8, co = i & 255;
      if (f32) cwT[i] = ((const float*)ps.p[10])[co * 64 + c];
      else     cwT[i] = b2f(((const bf16*)ps.p[10])[co * 64 + c]);
    }
    return;
  }
  if (s >= 18){
    static constexpr int srcs[5] = {2, 0, 4, 3, 12};
    const int src_slot = srcs[s - 18];
    bf16* dst = (s == 18) ? wdefb : (s == 19) ? woffb : (s == 20) ? wg1b
              : (s == 21) ? wcrossb : woutb;
    const int nsrc = (s == 19) ? 41472 : n[s];
    if (f32){
      const float* src = (const float*)ps.p[src_slot];
      for (int i = blockIdx.x * 256 + threadIdx.x; i < n[s]; i += gridDim.x * 256)
        dst[i] = (i < nsrc) ? __float2bfloat16(src[i]) : __float2bfloat16(0.f);
    } else {
      const bf16* src = (const bf16*)ps.p[src_slot];
      for (int i = blockIdx.x * 256 + threadIdx.x; i < n[s]; i += gridDim.x * 256)
        dst[i] = (i < nsrc) ? src[i] : __float2bfloat16(0.f);
    }
    return;
  }
  float* dst = cpar + off[s];
  if (f32){
    const float* src = (const float*)ps.p[s];
    for (int i = blockIdx.x * 256 + threadIdx.x; i < n[s]; i += gridDim.x * 256)
      dst[i] = src[i];
  } else {
    const bf16* src = (const bf16*)ps.p[s];
    for (int i = blockIdx.x * 256 + threadIdx.x; i < n[s]; i += gridDim.x * 256)
      dst[i] = b2f(src[i]);
  }
}

// ---------------------------------------------------------------------------
// K1b: NHWC staging for deform gather. x_t[b][g][p=4096][cg=64] f32.
// ---------------------------------------------------------------------------
template<typename T>
__device__ __forceinline__ void xt_body(const T* __restrict__ x, float* __restrict__ xt){
  __shared__ float lds[64][65];
  const int bx = blockIdx.x;
  const int b = bx >> 8, y = (bx >> 2) & 63, g = bx & 3;
  const int t = threadIdx.x;
  const int px = t & 63, cq = t >> 6;
  #pragma unroll
  for (int it = 0; it < 16; it++){
    const int ch = cq * 16 + it;
    lds[ch][px] = ldv(x, ((b * 256 + g * 64 + ch) * 64 + y) * 64 + px);
  }
  __syncthreads();
  const int ch = t & 63, pb = t >> 6;
  float* ob = xt + ((b * 4 + g) * 4096 + y * 64) * 64 + ch;
  #pragma unroll
  for (int i = 0; i < 16; i++){
    const int p = pb * 16 + i;
    ob[p * 64] = lds[ch][p];
  }
}

__global__ __launch_bounds__(256) void k_xt(const void* x, const int* flagp, float* xt){
  if (*flagp) xt_body((const float*)x, xt);
  else        xt_body((const bf16*)x, xt);
}

// ---------------------------------------------------------------------------
// Generic 3x3 pad=1 conv via im2col + MFMA — RAW split-K form.
// grid (256 = b*64+y, 4 = K-part). Each part covers 64 channels (2 chunks
// of 32ch x 9 taps) and writes a raw f32 partial (no bias/EPI). Partials
// are merged downstream (k_omerge / k_attn) in fixed deterministic order.
// ---------------------------------------------------------------------------
template<typename T, int COT>
__device__ __forceinline__ void conv3_raw(const T* __restrict__ xin,
    const bf16* __restrict__ wb, float* __restrict__ outp, int co_lim,
    unsigned short* cols, int cc_begin){
  const int bx = blockIdx.x;
  const int b = bx >> 6, y = bx & 63;
  const int t = threadIdx.x;
  const int l = t & 63, w = t >> 6;
  const int lm = l & 15, lq = l >> 4;
  const int pos2 = t & 31, kq = t >> 5;
  unsigned int* cols32 = (unsigned int*)cols;
  f32x4 acc[COT];
  #pragma unroll
  for (int m = 0; m < COT; m++) acc[m] = (f32x4){0.f,0.f,0.f,0.f};

  for (int cc = cc_begin; cc < cc_begin + 64; cc += 32){
    __syncthreads();
    #pragma unroll
    for (int c8 = 0; c8 < 4; c8++){
      const int c_local = kq * 4 + c8;
      const T* xc = xin + (b * 256 + cc + c_local) * 4096;
      #pragma unroll
      for (int tap = 0; tap < 9; tap++){
        const int ti = tap / 3, tj = tap % 3;
        const int yy = y + ti - 1;
        const int px0 = 2 * pos2 + tj - 1;
        const bool vy = (unsigned)yy < 64u;
        float v0 = (vy && (unsigned)px0 < 64u) ? ldv(xc, yy * 64 + px0) : 0.f;
        float v1 = (vy && (unsigned)(px0 + 1) < 64u) ? ldv(xc, yy * 64 + px0 + 1) : 0.f;
        bf16 h0 = __float2bfloat16(v0), h1 = __float2bfloat16(v1);
        unsigned int packed = (unsigned int)*(unsigned short*)&h0
                            | ((unsigned int)*(unsigned short*)&h1 << 16);
        cols32[(c_local * 9 + tap) * 34 + pos2] = packed;
      }
    }
    __syncthreads();
    #pragma unroll
    for (int kk = 0; kk < 288; kk += 32){
      short8 bfr;
      #pragma unroll
      for (int j = 0; j < 8; j++)
        bfr[j] = (short)cols[(kk + lq * 8 + j) * 68 + w * 16 + lm];
      #pragma unroll
      for (int m = 0; m < COT; m++){
        const bf16* ap = wb + (m * 16 + lm) * 2304 + cc * 9 + kk + lq * 8;
        short8 afr = *(const short8*)ap;
        acc[m] = __builtin_amdgcn_mfma_f32_16x16x32_bf16(afr, bfr, acc[m], 0, 0, 0);
      }
    }
  }
  const int p = y * 64 + w * 16 + lm;
  #pragma unroll
  for (int m = 0; m < COT; m++){
    #pragma unroll
    for (int r = 0; r < 4; r++){
      const int co = m * 16 + lq * 4 + r;
      if (co >= co_lim) continue;
      outp[(b * co_lim + co) * 4096 + p] = acc[m][r];
    }
  }
}

__global__ __launch_bounds__(256) void k_coff_m(const void* x, const int* flagp,
    const bf16* woffb, float* offp){
  __shared__ __align__(16) unsigned short cols[288 * 68];
  float* op = offp + blockIdx.y * 294912;
  const int cc0 = blockIdx.y * 64;
  if (*flagp) conv3_raw<float, 2>((const float*)x, woffb, op, 18, cols, cc0);
  else        conv3_raw<bf16, 2>((const bf16*)x, woffb, op, 18, cols, cc0);
}

__global__ __launch_bounds__(256) void k_g1_m(const float* xdense,
    const bf16* wg1b, float* abp){
  __shared__ __align__(16) unsigned short cols[288 * 68];
  float* op = abp + blockIdx.y * 1048576;
  conv3_raw<float, 4>(xdense, wg1b, op, 64, cols, blockIdx.y * 64);
}

// ---------------------------------------------------------------------------
// K1c: merge 4 offset partials + bias -> offc. 294912 f as float4.
// ---------------------------------------------------------------------------
__global__ __launch_bounds__(256) void k_omerge(const float* __restrict__ offp,
    const float* __restrict__ cb, float* __restrict__ offc){
  const int i4 = (blockIdx.x * 256 + threadIdx.x) * 4;
  constexpr int PS = 294912;
  f32x4 a = *(const f32x4*)(offp + i4);
  f32x4 b = *(const f32x4*)(offp + PS + i4);
  f32x4 c = *(const f32x4*)(offp + 2 * PS + i4);
  f32x4 d = *(const f32x4*)(offp + 3 * PS + i4);
  const int co = (i4 >> 12) % 18;
  const float bias = cb[co];
  f32x4 r;
  #pragma unroll
  for (int j = 0; j < 4; j++) r[j] = ((a[j] + b[j]) + c[j]) + d[j] + bias;
  *(f32x4*)(offc + i4) = r;
}

// ---------------------------------------------------------------------------
// K2: deformable conv, MFMA, fused, NHWC f32 gather (unchanged from R5).
// ---------------------------------------------------------------------------
#define CROW2 292

__global__ __launch_bounds__(256) void k_deform(const float* __restrict__ xt,
    const float* __restrict__ offc, const bf16* __restrict__ wdefb,
    float* __restrict__ xdir){
  __shared__ __align__(16) unsigned short cols[32 * CROW2];
  const int g = blockIdx.y;
  const int q0 = blockIdx.x * 32;
  const int b = q0 >> 12, p0 = q0 & 4095;
  const int t = threadIdx.x;
  const int pos = t & 31, u4 = t >> 5;
  const int c0 = u4 * 4;
  const int p = p0 + pos;
  const int y = p >> 6, xx = p & 63;
  const float* ob = offc + b * 18 * 4096 + p;
  const float* xg = xt + (b * 4 + g) * 4096 * 64;
  const int w = t >> 6;
  const int l = t & 63;
  const int lrow = l & 15;
  const int lhi = l >> 4;
  f32x4 acc0 = {0.f, 0.f, 0.f, 0.f};
  f32x4 acc1 = {0.f, 0.f, 0.f, 0.f};
  const bf16* wr = wdefb + (g * 64 + w * 16 + lrow) * 576;
  const unsigned short* b0p = cols + lrow * CROW2;
  const unsigned short* b1p = cols + (16 + lrow) * CROW2;

  #pragma unroll
  for (int half = 0; half < 2; half++){
    __syncthreads();
    const int hb = half * 32 + c0;
    #pragma unroll
    for (int k = 0; k < 9; k++){
      float dy = ob[(2 * k) * 4096];
      float dx = ob[(2 * k + 1) * 4096];
      float py = (float)(y + k / 3 - 1) + dy;
      float px = (float)(xx + k % 3 - 1) + dx;
      float y0f = floorf(py), x0f = floorf(px);
      int y0 = (int)y0f, x0 = (int)x0f;
      float wy1 = py - y0f, wx1 = px - x0f;
      float wy0 = 1.f - wy1, wx0 = 1.f - wx1;
      bool vy0 = (unsigned)y0 < 64u, vy1 = (unsigned)(y0 + 1) < 64u;
      bool vx0 = (unsigned)x0 < 64u, vx1 = (unsigned)(x0 + 1) < 64u;
      float w00 = (vy0 && vx0) ? wy0 * wx0 : 0.f;
      float w01 = (vy0 && vx1) ? wy0 * wx1 : 0.f;
      float w10 = (vy1 && vx0) ? wy1 * wx0 : 0.f;
      float w11 = (vy1 && vx1) ? wy1 * wx1 : 0.f;
      int yc0 = min(max(y0, 0), 63), yc1 = min(max(y0 + 1, 0), 63);
      int xc0 = min(max(x0, 0), 63), xc1 = min(max(x0 + 1, 0), 63);
      int i00 = yc0 * 64 + xc0, i01 = yc0 * 64 + xc1;
      int i10 = yc1 * 64 + xc0, i11 = yc1 * 64 + xc1;
      f32x4 v00 = *(const f32x4*)(xg + i00 * 64 + hb);
      f32x4 v01 = *(const f32x4*)(xg + i01 * 64 + hb);
      f32x4 v10 = *(const f32x4*)(xg + i10 * 64 + hb);
      f32x4 v11 = *(const f32x4*)(xg + i11 * 64 + hb);
      #pragma unroll
      for (int j = 0; j < 4; j++){
        float val = w00 * v00[j] + w01 * v01[j]
                  + w10 * v10[j] + w11 * v11[j];
        bf16 hv = __float2bfloat16(val);
        cols[pos * CROW2 + (c0 + j) * 9 + k] = *(unsigned short*)&hv;
      }
    }
    __syncthreads();
    const int kbase = half * 288;
    #pragma unroll 2
    for (int kk = 0; kk < 288; kk += 32){
      int ko = kk + lhi * 8;
      short8 a  = *(const short8*)(wr + kbase + ko);
      short8 b0 = *(const short8*)(b0p + ko);
      short8 b1 = *(const short8*)(b1p + ko);
      acc0 = __builtin_amdgcn_mfma_f32_16x16x32_bf16(a, b0, acc0, 0, 0, 0);
      acc1 = __builtin_amdgcn_mfma_f32_16x16x32_bf16(a, b1, acc1, 0, 0, 0);
    }
  }
  const int co_base = g * 64 + w * 16 + lhi * 4;
  #pragma unroll
  for (int r = 0; r < 4; r++){
    float* xo = xdir + (b * 256 + co_base + r) * 4096 + p0 + lrow;
    xo[0]  = acc0[r];
    xo[16] = acc1[r];
  }
}

// ---------------------------------------------------------------------------
// K3: 1x1 conv concat([x_dir, x_prev]) * w_cross (256x512) — MFMA.
// ---------------------------------------------------------------------------
template<typename T>
__device__ __forceinline__ void cross_mfma_body(const float* __restrict__ xdir,
    const T* __restrict__ xprev, const bf16* __restrict__ wb,
    float* __restrict__ xdense, unsigned short* cols){
  const int bx = blockIdx.x;
  const int b = bx >> 6, y = bx & 63;
  const int co0 = blockIdx.y * 128;
  const int t = threadIdx.x;
  const int l = t & 63, w = t >> 6;
  const int lm = l & 15, lq = l >> 4;
  const int pos2 = t & 31, cq = t >> 5;
  unsigned int* cols32 = (unsigned int*)cols;
  f32x4 acc[8];
  #pragma unroll
  for (int m = 0; m < 8; m++) acc[m] = (f32x4){0.f,0.f,0.f,0.f};

  for (int cc = 0; cc < 512; cc += 64){
    __syncthreads();
    #pragma unroll
    for (int c8 = 0; c8 < 8; c8++){
      const int cl = cq * 8 + c8;
      const int ci = cc + cl;
      float v0, v1;
      if (ci < 256){
        const float* row = xdir + (b * 256 + ci) * 4096 + y * 64 + 2 * pos2;
        v0 = row[0]; v1 = row[1];
      } else {
        const T* row = xprev + (b * 256 + (ci - 256)) * 4096 + y * 64 + 2 * pos2;
        v0 = ldv(row, 0); v1 = ldv(row, 1);
      }
      bf16 h0 = __float2bfloat16(v0), h1 = __float2bfloat16(v1);
      unsigned int packed = (unsigned int)*(unsigned short*)&h0
                          | ((unsigned int)*(unsigned short*)&h1 << 16);
      cols32[cl * 34 + pos2] = packed;
    }
    __syncthreads();
    #pragma unroll
    for (int kk = 0; kk < 64; kk += 32){
      short8 bfr;
      #pragma unroll
      for (int j = 0; j < 8; j++)
        bfr[j] = (short)cols[(kk + lq * 8 + j) * 68 + w * 16 + lm];
      #pragma unroll
      for (int m = 0; m < 8; m++){
        const bf16* ap = wb + (co0 + m * 16 + lm) * 512 + cc + kk + lq * 8;
        short8 afr = *(const short8*)ap;
        acc[m] = __builtin_amdgcn_mfma_f32_16x16x32_bf16(afr, bfr, acc[m], 0, 0, 0);
      }
    }
  }
  const int p = y * 64 + w * 16 + lm;
  #pragma unroll
  for (int m = 0; m < 8; m++){
    #pragma unroll
    for (int r = 0; r < 4; r++){
      const int co = co0 + m * 16 + lq * 4 + r;
      xdense[(b * 256 + co) * 4096 + p] = acc[m][r];
    }
  }
}

__global__ __launch_bounds__(256) void k_cross(const float* xdir, const void* xprev,
    const int* flagp, const bf16* wcb, float* xdense){
  __shared__ __align__(16) unsigned short cols[64 * 68];
  if (*flagp) cross_mfma_body(xdir, (const float*)xprev, wcb, xdense, cols);
  else        cross_mfma_body(xdir, (const bf16*)xprev, wcb, xdense, cols);
}

// ---------------------------------------------------------------------------
// K5: attn, restructured. grid (1024 = b*256 + pc), 256 thr. Stage the
// merged+bias+BN+SiLU a-tile [64ch][16px] in LDS once; each thread owns
// one co x 16 px, FMA chain over c ascending. cwT coalesced.
// ---------------------------------------------------------------------------
__global__ __launch_bounds__(256) void k_attn(const float* __restrict__ abp,
    const float* __restrict__ cb1, const float* __restrict__ gam,
    const float* __restrict__ bet, const float* __restrict__ mea,
    const float* __restrict__ var, const float* __restrict__ cwT,
    const float* __restrict__ cb2, const float* __restrict__ xdense,
    float* __restrict__ xa){
  __shared__ float a_s[64][17];
  const int bx = blockIdx.x;
  const int b = bx >> 8, pc = bx & 255;
  const int p0 = pc * 16;
  const int t = threadIdx.x;
  constexpr int PS = 1048576;
  {
    const int ch = t >> 2;
    const int px0 = (t & 3) * 4;
    const float inv = gam[ch] * rsqrtf(var[ch] + 1e-5f);
    const float sh  = bet[ch] - mea[ch] * inv;
    const float bias = cb1[ch];
    const int ai = (b * 64 + ch) * 4096 + p0 + px0;
    #pragma unroll
    for (int j = 0; j < 4; j++){
      float s = ((abp[ai + j] + abp[PS + ai + j]) + abp[2 * PS + ai + j])
              + abp[3 * PS + ai + j];
      s += bias;
      s = s * inv + sh;
      s = s * sigf(s);
      a_s[ch][px0 + j] = s;
    }
  }
  __syncthreads();
  const int co = t;
  float acc[16];
  #pragma unroll
  for (int i = 0; i < 16; i++) acc[i] = 0.f;
  for (int c = 0; c < 64; c++){
    const float wv = cwT[c * 256 + co];
    #pragma unroll
    for (int i = 0; i < 16; i++) acc[i] += wv * a_s[c][i];
  }
  const float bias2 = cb2[co];
  const int base = (b * 256 + co) * 4096 + p0;
  #pragma unroll
  for (int i = 0; i < 16; i++){
    float attn = sigf(acc[i] + bias2);
    xa[base + i] = xdense[base + i] * attn;
  }
}

// ---------------------------------------------------------------------------
// K6: 1x1 conv 256->256 + bias + BN + SiLU + residual — MFMA.
// ---------------------------------------------------------------------------
template<typename T>
__device__ __forceinline__ void out_mfma_body(const float* __restrict__ xa,
    const bf16* __restrict__ wb, const float* __restrict__ cbv,
    const float* __restrict__ gam, const float* __restrict__ bet,
    const float* __restrict__ mea, const float* __restrict__ var,
    const T* __restrict__ xres, T* __restrict__ outp, unsigned short* cols){
  const int bx = blockIdx.x;
  const int b = bx >> 6, y = bx & 63;
  const int co0 = blockIdx.y * 128;
  const int t = threadIdx.x;
  const int l = t & 63, w = t >> 6;
  const int lm = l & 15, lq = l >> 4;
  const int pos2 = t & 31, cq = t >> 5;
  unsigned int* cols32 = (unsigned int*)cols;
  f32x4 acc[8];
  #pragma unroll
  for (int m = 0; m < 8; m++) acc[m] = (f32x4){0.f,0.f,0.f,0.f};

  for (int cc = 0; cc < 256; cc += 64){
    __syncthreads();
    #pragma unroll
    for (int c8 = 0; c8 < 8; c8++){
      const int cl = cq * 8 + c8;
      const int ci = cc + cl;
      const float* row = xa + (b * 256 + ci) * 4096 + y * 64 + 2 * pos2;
      float v0 = row[0], v1 = row[1];
      bf16 h0 = __float2bfloat16(v0), h1 = __float2bfloat16(v1);
      unsigned int packed = (unsigned int)*(unsigned short*)&h0
                          | ((unsigned int)*(unsigned short*)&h1 << 16);
      cols32[cl * 34 + pos2] = packed;
    }
    __syncthreads();
    #pragma unroll
    for (int kk = 0; kk < 64; kk += 32){
      short8 bfr;
      #pragma unroll
      for (int j = 0; j < 8; j++)
        bfr[j] = (short)cols[(kk + lq * 8 + j) * 68 + w * 16 + lm];
      #pragma unroll
      for (int m = 0; m < 8; m++){
        const bf16* ap = wb + (co0 + m * 16 + lm) * 256 + cc + kk + lq * 8;
        short8 afr = *(const short8*)ap;
        acc[m] = __builtin_amdgcn_mfma_f32_16x16x32_bf16(afr, bfr, acc[m], 0, 0, 0);
      }
    }
  }
  const int p = y * 64 + w * 16 + lm;
  #pragma unroll
  for (int m = 0; m < 8; m++){
    #pragma unroll
    for (int r = 0; r < 4; r++){
      const int co = co0 + m * 16 + lq * 4 + r;
      float inv = gam[co] * rsqrtf(var[co] + 1e-5f);
      float v = acc[m][r] + cbv[co];
      v = v * inv + (bet[co] - mea[co] * inv);
      v = v * sigf(v);
      const int idx = (b * 256 + co) * 4096 + p;
      stv(outp, idx, v + ldv(xres, idx));
    }
  }
}

__global__ __launch_bounds__(256) void k_out(const float* xa, const bf16* wob,
    const float* cb, const float* gam, const float* bet, const float* mea,
    const float* var, const void* xres, void* out, const int* flagp){
  __shared__ __align__(16) unsigned short cols[64 * 68];
  if (*flagp) out_mfma_body(xa, wob, cb, gam, bet, mea, var,
                            (const float*)xres, (float*)out, cols);
  else        out_mfma_body(xa, wob, cb, gam, bet, mea, var,
                            (const bf16*)xres, (bf16*)out, cols);
}

// ---------------------------------------------------------------------------
extern "C" void kernel_launch(void* const* d_in, const int* in_sizes, int n_in,
                              void* d_out, int out_size, void* d_ws, size_t ws_size,
                              hipStream_t stream) {
  const void* x      = d_in[0];
  const void* x_prev = d_in[1];

  float* ws   = (float*)d_ws;
  int*   flag = (int*)ws;                 // ws[0..15] reserved
  float* cpar = ws + 16;                  // canonical fp32 params (551264 f)
  float* cb_off   = cpar + 41472;
  float* cb_g1    = cpar + 467488;
  float* cg1_gam  = cpar + 467552;
  float* cg1_bet  = cpar + 467616;
  float* cg1_mea  = cpar + 467680;
  float* cg1_var  = cpar + 467744;
  float* cb_g2    = cpar + 484192;
  float* cb_out   = cpar + 549984;
  float* co_gam   = cpar + 550240;
  float* co_bet   = cpar + 550496;
  float* co_mea   = cpar + 550752;
  float* co_var   = cpar + 551008;

  float* cwT     = ws + 16 + 551264;                // 16384 f (w_g2 transposed)
  bf16*  wdefb   = (bf16*)(ws + 567664);            // 73728 f
  bf16*  woffb   = (bf16*)(ws + 641392);            // 36864 f
  bf16*  wg1b    = (bf16*)(ws + 678256);            // 73728 f
  bf16*  wcrossb = (bf16*)(ws + 751984);            // 65536 f
  bf16*  woutb   = (bf16*)(ws + 817520);            // 32768 f
  float* base    = ws + 850288;
  float* offp   = base;                   // 4 x 294912  = 1179648 f
  float* offc   = offp + 1179648;         // 294912 f
  float* xdir   = offc + 294912;          // 4194304 f
  float* xdense = xdir + 4194304;         // 4194304 f
  float* abp    = xdense + 4194304;       // 4 x 1048576 = 4194304 f
  float* xt     = abp + 4194304;          // 4194304 f (NHWC)
  float* xa     = xdir;                   // reuse (xdir dead after K3)

  ParamSrc ps;
  for (int i = 0; i < 18; i++) ps.p[i] = d_in[2 + i];

  k_detect<<<dim3(1), 256, 0, stream>>>((const unsigned short*)x, flag);
  k_convert<<<dim3(96, 24), 256, 0, stream>>>(ps, flag, cpar, wdefb, woffb,
                                              wg1b, wcrossb, woutb, cwT);
  k_xt<<<dim3(1024), 256, 0, stream>>>(x, flag, xt);
  k_coff_m<<<dim3(256, 4), 256, 0, stream>>>(x, flag, woffb, offp);
  k_omerge<<<dim3(288), 256, 0, stream>>>(offp, cb_off, offc);
  k_deform<<<dim3(512, 4), 256, 0, stream>>>(xt, offc, wdefb, xdir);
  k_cross<<<dim3(256, 2), 256, 0, stream>>>(xdir, x_prev, flag, wcrossb, xdense);
  k_g1_m<<<dim3(256, 4), 256, 0, stream>>>(xdense, wg1b, abp);
  k_attn<<<dim3(1024), 256, 0, stream>>>(abp, cb_g1, cg1_gam, cg1_bet, cg1_mea,
                                         cg1_var, cwT, cb_g2, xdense, xa);
  k_out<<<dim3(256, 2), 256, 0, stream>>>(xa, woutb, cb_out, co_gam, co_bet,
                                          co_mea, co_var, x, d_out, flag);
}

// Round 9
// 393.746 us; speedup vs baseline: 1.3720x; 1.0793x over previous
//
#include <hip/hip_runtime.h>
#include <hip/hip_bf16.h>

using bf16 = __hip_bfloat16;
typedef __attribute__((ext_vector_type(8))) short short8;
typedef __attribute__((ext_vector_type(4))) float f32x4;

__device__ __forceinline__ float b2f(bf16 v){ return __bfloat162float(v); }
__device__ __forceinline__ float sigf(float v){ return 1.f/(1.f + __expf(-v)); }
__device__ __forceinline__ float ldv(const float* p, int i){ return p[i]; }
__device__ __forceinline__ float ldv(const bf16* p, int i){ return b2f(p[i]); }
__device__ __forceinline__ void stv(float* p, int i, float v){ p[i] = v; }
__device__ __forceinline__ void stv(bf16* p, int i, float v){ p[i] = __float2bfloat16(v); }

// load 2 adjacent values as one instruction (8B f32 / 4B bf16)
__device__ __forceinline__ void ld2v(const float* p, float& a, float& b){
  float2 v = *(const float2*)p; a = v.x; b = v.y;
}
__device__ __forceinline__ void ld2v(const bf16* p, float& a, float& b){
  unsigned int u = *(const unsigned int*)p;
  unsigned short s0 = (unsigned short)(u & 0xFFFF), s1 = (unsigned short)(u >> 16);
  a = b2f(*(bf16*)&s0); b = b2f(*(bf16*)&s1);
}
// load 8 adjacent values, return 4 packed bf16-pairs
__device__ __forceinline__ void ld8(const bf16* s, unsigned int* pk){
  short8 v = *(const short8*)s;
  #pragma unroll
  for (int e = 0; e < 4; e++)
    pk[e] = (unsigned int)(unsigned short)v[2*e]
          | ((unsigned int)(unsigned short)v[2*e+1] << 16);
}
__device__ __forceinline__ void ld8(const float* s, unsigned int* pk){
  f32x4 a = *(const f32x4*)s, c = *(const f32x4*)(s + 4);
  float vals[8] = {a[0],a[1],a[2],a[3],c[0],c[1],c[2],c[3]};
  #pragma unroll
  for (int e = 0; e < 4; e++){
    bf16 h0 = __float2bfloat16(vals[2*e]), h1 = __float2bfloat16(vals[2*e+1]);
    pk[e] = (unsigned int)*(unsigned short*)&h0
          | ((unsigned int)*(unsigned short*)&h1 << 16);
  }
}

// ---------------------------------------------------------------------------
// K0: dtype detect. flag=1 => inputs are f32.
// ---------------------------------------------------------------------------
__global__ __launch_bounds__(256) void k_detect(const unsigned short* xs, int* flag){
  __shared__ int cnt;
  if (threadIdx.x == 0) cnt = 0;
  __syncthreads();
  int local = 0;
  for (int i = threadIdx.x; i < 16384; i += 256){
    if (((xs[i] >> 7) & 0xFF) == 0xFF) local++;
  }
  if (local) atomicAdd(&cnt, local);
  __syncthreads();
  if (threadIdx.x == 0) *flag = (cnt > 0) ? 1 : 0;
}

// ---------------------------------------------------------------------------
// K0b: canonicalize params. slots 0-17: fp32 in cpar; 18-22: bf16 weights
// (19/20 = w_off/w_g1 REMAPPED to tap-major [co][chunk][tap][c32] for the
// tile-staged conv3); 23: w_g2 (input slot 10) transposed fp32. grid (96,24).
// ---------------------------------------------------------------------------
struct ParamSrc { const void* p[18]; };

__global__ __launch_bounds__(256) void k_convert(ParamSrc ps, const int* flagp,
    float* cpar, bf16* wdefb, bf16* woffb, bf16* wg1b, bf16* wcrossb, bf16* woutb,
    float* cwT){
  static constexpr int n[24]   = {41472,18,147456,131072,147456,64,64,64,64,64,
                                  16384,256,65536,256,256,256,256,256,
                                  147456,73728,147456,131072,65536,16384};
  static constexpr int off[18] = {0,41472,41504,188960,320032,467488,467552,467616,
                                  467680,467744,467808,484192,484448,549984,550240,
                                  550496,550752,551008};
  const int s = blockIdx.y;
  const bool f32 = (*flagp != 0);
  if (s == 23){
    for (int i = blockIdx.x * 256 + threadIdx.x; i < 16384; i += gridDim.x * 256){
      const int c = i >> 8, co = i & 255;
      if (f32) cwT[i] = ((const float*)ps.p[10])[co * 64 + c];
      else     cwT[i] = b2f(((const bf16*)ps.p[10])[co * 64 + c]);
    }
    return;
  }
  if (s >= 18){
    static constexpr int srcs[5] = {2, 0, 4, 3, 12};
    const int src_slot = srcs[s - 18];
    bf16* dst = (s == 18) ? wdefb : (s == 19) ? woffb : (s == 20) ? wg1b
              : (s == 21) ? wcrossb : woutb;
    const int nsrc = (s == 19) ? 41472 : n[s];
    const bool remap = (s == 19 || s == 20);
    for (int i = blockIdx.x * 256 + threadIdx.x; i < n[s]; i += gridDim.x * 256){
      int srcIdx = i;
      if (remap){
        const int co = i / 2304, rem = i % 2304;
        const int chunk = rem / 288, r2 = rem % 288;
        const int tap = r2 >> 5, cl = r2 & 31;
        srcIdx = co * 2304 + (chunk * 32 + cl) * 9 + tap;
      }
      if (f32){
        const float* src = (const float*)ps.p[src_slot];
        dst[i] = (srcIdx < nsrc) ? __float2bfloat16(src[srcIdx]) : __float2bfloat16(0.f);
      } else {
        const bf16* src = (const bf16*)ps.p[src_slot];
        dst[i] = (srcIdx < nsrc) ? src[srcIdx] : __float2bfloat16(0.f);
      }
    }
    return;
  }
  float* dst = cpar + off[s];
  if (f32){
    const float* src = (const float*)ps.p[s];
    for (int i = blockIdx.x * 256 + threadIdx.x; i < n[s]; i += gridDim.x * 256)
      dst[i] = src[i];
  } else {
    const bf16* src = (const bf16*)ps.p[s];
    for (int i = blockIdx.x * 256 + threadIdx.x; i < n[s]; i += gridDim.x * 256)
      dst[i] = b2f(src[i]);
  }
}

// ---------------------------------------------------------------------------
// K1b: NHWC staging for deform gather. x_t[b][g][p=4096][cg=64] f32.
// ---------------------------------------------------------------------------
template<typename T>
__device__ __forceinline__ void xt_body(const T* __restrict__ x, float* __restrict__ xt){
  __shared__ float lds[64][65];
  const int bx = blockIdx.x;
  const int b = bx >> 8, y = (bx >> 2) & 63, g = bx & 3;
  const int t = threadIdx.x;
  const int px = t & 63, cq = t >> 6;
  #pragma unroll
  for (int it = 0; it < 16; it++){
    const int ch = cq * 16 + it;
    lds[ch][px] = ldv(x, ((b * 256 + g * 64 + ch) * 64 + y) * 64 + px);
  }
  __syncthreads();
  const int ch = t & 63, pb = t >> 6;
  float* ob = xt + ((b * 4 + g) * 4096 + y * 64) * 64 + ch;
  #pragma unroll
  for (int i = 0; i < 16; i++){
    const int p = pb * 16 + i;
    ob[p * 64] = lds[ch][p];
  }
}

__global__ __launch_bounds__(256) void k_xt(const void* x, const int* flagp, float* xt){
  if (*flagp) xt_body((const float*)x, xt);
  else        xt_body((const bf16*)x, xt);
}

// ---------------------------------------------------------------------------
// conv3 RAW split-K, TILE-STAGED form. grid (256 = b*64+y, 4 = K-part).
// Per 32-ch chunk: stage [32c][3row][64px] bf16 tile via 16B loads (6/thread)
// into LDS pitch 70 (data cols 4..67; cols 3 & 68 zeroed => branch-free tap
// shifts; OOB rows zeroed). MFMA k-order = tap-major (tap*32+c), matching
// the remapped weights; B-frag read tile[c][ti][3+px+tj] is conflict-free
// (lq groups hit disjoint bank octets: c-stride 105 dw, x8 => 8 mod 32).
// ---------------------------------------------------------------------------
template<typename T, int COT>
__device__ __forceinline__ void conv3_raw(const T* __restrict__ xin,
    const bf16* __restrict__ wb, float* __restrict__ outp, int co_lim,
    unsigned short* xt16, int cc_begin){
  const int bx = blockIdx.x;
  const int b = bx >> 6, y = bx & 63;
  const int t = threadIdx.x;
  const int l = t & 63, w = t >> 6;
  const int lm = l & 15, lq = l >> 4;
  const int px = w * 16 + lm;
  f32x4 acc[COT];
  #pragma unroll
  for (int m = 0; m < COT; m++) acc[m] = (f32x4){0.f,0.f,0.f,0.f};

  #pragma unroll
  for (int ch_i = 0; ch_i < 2; ch_i++){
    const int cc = cc_begin + ch_i * 32;
    __syncthreads();
    if (t < 96){
      const int c = t / 3, r = t - c * 3;
      xt16[c * 210 + r * 70 + 3]  = 0;
      xt16[c * 210 + r * 70 + 68] = 0;
    }
    #pragma unroll
    for (int it = 0; it < 3; it++){
      const int u = t + it * 256;
      const int pb = u & 7;
      const int cr = u >> 3;
      const int c = cr / 3, r = cr - c * 3;
      const int yy = y + r - 1;
      const int px0 = pb * 8;
      unsigned int pk[4];
      if ((unsigned)yy < 64u){
        ld8(xin + (b * 256 + cc + c) * 4096 + yy * 64 + px0, pk);
      } else {
        pk[0] = pk[1] = pk[2] = pk[3] = 0;
      }
      unsigned int* dp = (unsigned int*)(xt16 + c * 210 + r * 70 + 4 + px0);
      dp[0] = pk[0]; dp[1] = pk[1]; dp[2] = pk[2]; dp[3] = pk[3];
    }
    __syncthreads();
    const int chunkG = cc >> 5;
    const unsigned short* bt = xt16 + 3 + px;
    #pragma unroll
    for (int tap = 0; tap < 9; tap++){
      const int ti = tap / 3, tj = tap - ti * 3;
      short8 bfr;
      #pragma unroll
      for (int j = 0; j < 8; j++)
        bfr[j] = (short)bt[(lq * 8 + j) * 210 + ti * 70 + tj];
      #pragma unroll
      for (int m = 0; m < COT; m++){
        const bf16* ap = wb + (m * 16 + lm) * 2304 + chunkG * 288 + tap * 32 + lq * 8;
        short8 afr = *(const short8*)ap;
        acc[m] = __builtin_amdgcn_mfma_f32_16x16x32_bf16(afr, bfr, acc[m], 0, 0, 0);
      }
    }
  }
  const int p = y * 64 + px;
  #pragma unroll
  for (int m = 0; m < COT; m++){
    #pragma unroll
    for (int r = 0; r < 4; r++){
      const int co = m * 16 + lq * 4 + r;
      if (co >= co_lim) continue;
      outp[(b * co_lim + co) * 4096 + p] = acc[m][r];
    }
  }
}

__global__ __launch_bounds__(256) void k_coff_m(const void* x, const int* flagp,
    const bf16* woffb, float* offp){
  __shared__ __align__(16) unsigned short xtile[32 * 210];
  float* op = offp + blockIdx.y * 294912;
  const int cc0 = blockIdx.y * 64;
  if (*flagp) conv3_raw<float, 2>((const float*)x, woffb, op, 18, xtile, cc0);
  else        conv3_raw<bf16, 2>((const bf16*)x, woffb, op, 18, xtile, cc0);
}

__global__ __launch_bounds__(256) void k_g1_m(const float* xdense,
    const bf16* wg1b, float* abp){
  __shared__ __align__(16) unsigned short xtile[32 * 210];
  float* op = abp + blockIdx.y * 1048576;
  conv3_raw<float, 4>(xdense, wg1b, op, 64, xtile, blockIdx.y * 64);
}

// ---------------------------------------------------------------------------
// K1c: merge 4 offset partials + bias -> offc. 294912 f as float4.
// ---------------------------------------------------------------------------
__global__ __launch_bounds__(256) void k_omerge(const float* __restrict__ offp,
    const float* __restrict__ cb, float* __restrict__ offc){
  const int i4 = (blockIdx.x * 256 + threadIdx.x) * 4;
  constexpr int PS = 294912;
  f32x4 a = *(const f32x4*)(offp + i4);
  f32x4 b = *(const f32x4*)(offp + PS + i4);
  f32x4 c = *(const f32x4*)(offp + 2 * PS + i4);
  f32x4 d = *(const f32x4*)(offp + 3 * PS + i4);
  const int co = (i4 >> 12) % 18;
  const float bias = cb[co];
  f32x4 r;
  #pragma unroll
  for (int j = 0; j < 4; j++) r[j] = ((a[j] + b[j]) + c[j]) + d[j] + bias;
  *(f32x4*)(offc + i4) = r;
}

// ---------------------------------------------------------------------------
// K2: deformable conv, MFMA, fused, NHWC f32 gather (unchanged).
// ---------------------------------------------------------------------------
#define CROW2 292

__global__ __launch_bounds__(256) void k_deform(const float* __restrict__ xt,
    const float* __restrict__ offc, const bf16* __restrict__ wdefb,
    float* __restrict__ xdir){
  __shared__ __align__(16) unsigned short cols[32 * CROW2];
  const int g = blockIdx.y;
  const int q0 = blockIdx.x * 32;
  const int b = q0 >> 12, p0 = q0 & 4095;
  const int t = threadIdx.x;
  const int pos = t & 31, u4 = t >> 5;
  const int c0 = u4 * 4;
  const int p = p0 + pos;
  const int y = p >> 6, xx = p & 63;
  const float* ob = offc + b * 18 * 4096 + p;
  const float* xg = xt + (b * 4 + g) * 4096 * 64;
  const int w = t >> 6;
  const int l = t & 63;
  const int lrow = l & 15;
  const int lhi = l >> 4;
  f32x4 acc0 = {0.f, 0.f, 0.f, 0.f};
  f32x4 acc1 = {0.f, 0.f, 0.f, 0.f};
  const bf16* wr = wdefb + (g * 64 + w * 16 + lrow) * 576;
  const unsigned short* b0p = cols + lrow * CROW2;
  const unsigned short* b1p = cols + (16 + lrow) * CROW2;

  #pragma unroll
  for (int half = 0; half < 2; half++){
    __syncthreads();
    const int hb = half * 32 + c0;
    #pragma unroll
    for (int k = 0; k < 9; k++){
      float dy = ob[(2 * k) * 4096];
      float dx = ob[(2 * k + 1) * 4096];
      float py = (float)(y + k / 3 - 1) + dy;
      float px = (float)(xx + k % 3 - 1) + dx;
      float y0f = floorf(py), x0f = floorf(px);
      int y0 = (int)y0f, x0 = (int)x0f;
      float wy1 = py - y0f, wx1 = px - x0f;
      float wy0 = 1.f - wy1, wx0 = 1.f - wx1;
      bool vy0 = (unsigned)y0 < 64u, vy1 = (unsigned)(y0 + 1) < 64u;
      bool vx0 = (unsigned)x0 < 64u, vx1 = (unsigned)(x0 + 1) < 64u;
      float w00 = (vy0 && vx0) ? wy0 * wx0 : 0.f;
      float w01 = (vy0 && vx1) ? wy0 * wx1 : 0.f;
      float w10 = (vy1 && vx0) ? wy1 * wx0 : 0.f;
      float w11 = (vy1 && vx1) ? wy1 * wx1 : 0.f;
      int yc0 = min(max(y0, 0), 63), yc1 = min(max(y0 + 1, 0), 63);
      int xc0 = min(max(x0, 0), 63), xc1 = min(max(x0 + 1, 0), 63);
      int i00 = yc0 * 64 + xc0, i01 = yc0 * 64 + xc1;
      int i10 = yc1 * 64 + xc0, i11 = yc1 * 64 + xc1;
      f32x4 v00 = *(const f32x4*)(xg + i00 * 64 + hb);
      f32x4 v01 = *(const f32x4*)(xg + i01 * 64 + hb);
      f32x4 v10 = *(const f32x4*)(xg + i10 * 64 + hb);
      f32x4 v11 = *(const f32x4*)(xg + i11 * 64 + hb);
      #pragma unroll
      for (int j = 0; j < 4; j++){
        float val = w00 * v00[j] + w01 * v01[j]
                  + w10 * v10[j] + w11 * v11[j];
        bf16 hv = __float2bfloat16(val);
        cols[pos * CROW2 + (c0 + j) * 9 + k] = *(unsigned short*)&hv;
      }
    }
    __syncthreads();
    const int kbase = half * 288;
    #pragma unroll 2
    for (int kk = 0; kk < 288; kk += 32){
      int ko = kk + lhi * 8;
      short8 a  = *(const short8*)(wr + kbase + ko);
      short8 b0 = *(const short8*)(b0p + ko);
      short8 b1 = *(const short8*)(b1p + ko);
      acc0 = __builtin_amdgcn_mfma_f32_16x16x32_bf16(a, b0, acc0, 0, 0, 0);
      acc1 = __builtin_amdgcn_mfma_f32_16x16x32_bf16(a, b1, acc1, 0, 0, 0);
    }
  }
  const int co_base = g * 64 + w * 16 + lhi * 4;
  #pragma unroll
  for (int r = 0; r < 4; r++){
    float* xo = xdir + (b * 256 + co_base + r) * 4096 + p0 + lrow;
    xo[0]  = acc0[r];
    xo[16] = acc1[r];
  }
}

// ---------------------------------------------------------------------------
// K3: 1x1 conv concat([x_dir, x_prev]) * w_cross (256x512) — MFMA.
// R8->R9: staging loads vectorized (float2 / packed bf16x2).
// ---------------------------------------------------------------------------
template<typename T>
__device__ __forceinline__ void cross_mfma_body(const float* __restrict__ xdir,
    const T* __restrict__ xprev, const bf16* __restrict__ wb,
    float* __restrict__ xdense, unsigned short* cols){
  const int bx = blockIdx.x;
  const int b = bx >> 6, y = bx & 63;
  const int co0 = blockIdx.y * 128;
  const int t = threadIdx.x;
  const int l = t & 63, w = t >> 6;
  const int lm = l & 15, lq = l >> 4;
  const int pos2 = t & 31, cq = t >> 5;
  unsigned int* cols32 = (unsigned int*)cols;
  f32x4 acc[8];
  #pragma unroll
  for (int m = 0; m < 8; m++) acc[m] = (f32x4){0.f,0.f,0.f,0.f};

  for (int cc = 0; cc < 512; cc += 64){
    __syncthreads();
    #pragma unroll
    for (int c8 = 0; c8 < 8; c8++){
      const int cl = cq * 8 + c8;
      const int ci = cc + cl;
      float v0, v1;
      if (ci < 256) ld2v(xdir + (b * 256 + ci) * 4096 + y * 64 + 2 * pos2, v0, v1);
      else          ld2v(xprev + (b * 256 + (ci - 256)) * 4096 + y * 64 + 2 * pos2, v0, v1);
      bf16 h0 = __float2bfloat16(v0), h1 = __float2bfloat16(v1);
      unsigned int packed = (unsigned int)*(unsigned short*)&h0
                          | ((unsigned int)*(unsigned short*)&h1 << 16);
      cols32[cl * 34 + pos2] = packed;
    }
    __syncthreads();
    #pragma unroll
    for (int kk = 0; kk < 64; kk += 32){
      short8 bfr;
      #pragma unroll
      for (int j = 0; j < 8; j++)
        bfr[j] = (short)cols[(kk + lq * 8 + j) * 68 + w * 16 + lm];
      #pragma unroll
      for (int m = 0; m < 8; m++){
        const bf16* ap = wb + (co0 + m * 16 + lm) * 512 + cc + kk + lq * 8;
        short8 afr = *(const short8*)ap;
        acc[m] = __builtin_amdgcn_mfma_f32_16x16x32_bf16(afr, bfr, acc[m], 0, 0, 0);
      }
    }
  }
  const int p = y * 64 + w * 16 + lm;
  #pragma unroll
  for (int m = 0; m < 8; m++){
    #pragma unroll
    for (int r = 0; r < 4; r++){
      const int co = co0 + m * 16 + lq * 4 + r;
      xdense[(b * 256 + co) * 4096 + p] = acc[m][r];
    }
  }
}

__global__ __launch_bounds__(256) void k_cross(const float* xdir, const void* xprev,
    const int* flagp, const bf16* wcb, float* xdense){
  __shared__ __align__(16) unsigned short cols[64 * 68];
  if (*flagp) cross_mfma_body(xdir, (const float*)xprev, wcb, xdense, cols);
  else        cross_mfma_body(xdir, (const bf16*)xprev, wcb, xdense, cols);
}

// ---------------------------------------------------------------------------
// K5: attn (R8 structure, passing). grid (1024), 256 thr.
// ---------------------------------------------------------------------------
__global__ __launch_bounds__(256) void k_attn(const float* __restrict__ abp,
    const float* __restrict__ cb1, const float* __restrict__ gam,
    const float* __restrict__ bet, const float* __restrict__ mea,
    const float* __restrict__ var, const float* __restrict__ cwT,
    const float* __restrict__ cb2, const float* __restrict__ xdense,
    float* __restrict__ xa){
  __shared__ float a_s[64][17];
  const int bx = blockIdx.x;
  const int b = bx >> 8, pc = bx & 255;
  const int p0 = pc * 16;
  const int t = threadIdx.x;
  constexpr int PS = 1048576;
  {
    const int ch = t >> 2;
    const int px0 = (t & 3) * 4;
    const float inv = gam[ch] * rsqrtf(var[ch] + 1e-5f);
    const float sh  = bet[ch] - mea[ch] * inv;
    const float bias = cb1[ch];
    const int ai = (b * 64 + ch) * 4096 + p0 + px0;
    #pragma unroll
    for (int j = 0; j < 4; j++){
      float s = ((abp[ai + j] + abp[PS + ai + j]) + abp[2 * PS + ai + j])
              + abp[3 * PS + ai + j];
      s += bias;
      s = s * inv + sh;
      s = s * sigf(s);
      a_s[ch][px0 + j] = s;
    }
  }
  __syncthreads();
  const int co = t;
  float acc[16];
  #pragma unroll
  for (int i = 0; i < 16; i++) acc[i] = 0.f;
  for (int c = 0; c < 64; c++){
    const float wv = cwT[c * 256 + co];
    #pragma unroll
    for (int i = 0; i < 16; i++) acc[i] += wv * a_s[c][i];
  }
  const float bias2 = cb2[co];
  const int base = (b * 256 + co) * 4096 + p0;
  #pragma unroll
  for (int i = 0; i < 16; i++){
    float attn = sigf(acc[i] + bias2);
    xa[base + i] = xdense[base + i] * attn;
  }
}

// ---------------------------------------------------------------------------
// K6: 1x1 conv 256->256 + bias + BN + SiLU + residual — MFMA.
// R8->R9: staging loads vectorized (float2).
// ---------------------------------------------------------------------------
template<typename T>
__device__ __forceinline__ void out_mfma_body(const float* __restrict__ xa,
    const bf16* __restrict__ wb, const float* __restrict__ cbv,
    const float* __restrict__ gam, const float* __restrict__ bet,
    const float* __restrict__ mea, const float* __restrict__ var,
    const T* __restrict__ xres, T* __restrict__ outp, unsigned short* cols){
  const int bx = blockIdx.x;
  const int b = bx >> 6, y = bx & 63;
  const int co0 = blockIdx.y * 128;
  const int t = threadIdx.x;
  const int l = t & 63, w = t >> 6;
  const int lm = l & 15, lq = l >> 4;
  const int pos2 = t & 31, cq = t >> 5;
  unsigned int* cols32 = (unsigned int*)cols;
  f32x4 acc[8];
  #pragma unroll
  for (int m = 0; m < 8; m++) acc[m] = (f32x4){0.f,0.f,0.f,0.f};

  for (int cc = 0; cc < 256; cc += 64){
    __syncthreads();
    #pragma unroll
    for (int c8 = 0; c8 < 8; c8++){
      const int cl = cq * 8 + c8;
      const int ci = cc + cl;
      float v0, v1;
      ld2v(xa + (b * 256 + ci) * 4096 + y * 64 + 2 * pos2, v0, v1);
      bf16 h0 = __float2bfloat16(v0), h1 = __float2bfloat16(v1);
      unsigned int packed = (unsigned int)*(unsigned short*)&h0
                          | ((unsigned int)*(unsigned short*)&h1 << 16);
      cols32[cl * 34 + pos2] = packed;
    }
    __syncthreads();
    #pragma unroll
    for (int kk = 0; kk < 64; kk += 32){
      short8 bfr;
      #pragma unroll
      for (int j = 0; j < 8; j++)
        bfr[j] = (short)cols[(kk + lq * 8 + j) * 68 + w * 16 + lm];
      #pragma unroll
      for (int m = 0; m < 8; m++){
        const bf16* ap = wb + (co0 + m * 16 + lm) * 256 + cc + kk + lq * 8;
        short8 afr = *(const short8*)ap;
        acc[m] = __builtin_amdgcn_mfma_f32_16x16x32_bf16(afr, bfr, acc[m], 0, 0, 0);
      }
    }
  }
  const int p = y * 64 + w * 16 + lm;
  #pragma unroll
  for (int m = 0; m < 8; m++){
    #pragma unroll
    for (int r = 0; r < 4; r++){
      const int co = co0 + m * 16 + lq * 4 + r;
      float inv = gam[co] * rsqrtf(var[co] + 1e-5f);
      float v = acc[m][r] + cbv[co];
      v = v * inv + (bet[co] - mea[co] * inv);
      v = v * sigf(v);
      const int idx = (b * 256 + co) * 4096 + p;
      stv(outp, idx, v + ldv(xres, idx));
    }
  }
}

__global__ __launch_bounds__(256) void k_out(const float* xa, const bf16* wob,
    const float* cb, const float* gam, const float* bet, const float* mea,
    const float* var, const void* xres, void* out, const int* flagp){
  __shared__ __align__(16) unsigned short cols[64 * 68];
  if (*flagp) out_mfma_body(xa, wob, cb, gam, bet, mea, var,
                            (const float*)xres, (float*)out, cols);
  else        out_mfma_body(xa, wob, cb, gam, bet, mea, var,
                            (const bf16*)xres, (bf16*)out, cols);
}

// ---------------------------------------------------------------------------
extern "C" void kernel_launch(void* const* d_in, const int* in_sizes, int n_in,
                              void* d_out, int out_size, void* d_ws, size_t ws_size,
                              hipStream_t stream) {
  const void* x      = d_in[0];
  const void* x_prev = d_in[1];

  float* ws   = (float*)d_ws;
  int*   flag = (int*)ws;                 // ws[0..15] reserved
  float* cpar = ws + 16;                  // canonical fp32 params (551264 f)
  float* cb_off   = cpar + 41472;
  float* cb_g1    = cpar + 467488;
  float* cg1_gam  = cpar + 467552;
  float* cg1_bet  = cpar + 467616;
  float* cg1_mea  = cpar + 467680;
  float* cg1_var  = cpar + 467744;
  float* cb_g2    = cpar + 484192;
  float* cb_out   = cpar + 549984;
  float* co_gam   = cpar + 550240;
  float* co_bet   = cpar + 550496;
  float* co_mea   = cpar + 550752;
  float* co_var   = cpar + 551008;

  float* cwT     = ws + 16 + 551264;                // 16384 f (w_g2 transposed)
  bf16*  wdefb   = (bf16*)(ws + 567664);            // 73728 f
  bf16*  woffb   = (bf16*)(ws + 641392);            // 36864 f
  bf16*  wg1b    = (bf16*)(ws + 678256);            // 73728 f
  bf16*  wcrossb = (bf16*)(ws + 751984);            // 65536 f
  bf16*  woutb   = (bf16*)(ws + 817520);            // 32768 f
  float* base    = ws + 850288;
  float* offp   = base;                   // 4 x 294912  = 1179648 f
  float* offc   = offp + 1179648;         // 294912 f
  float* xdir   = offc + 294912;          // 4194304 f
  float* xdense = xdir + 4194304;         // 4194304 f
  float* abp    = xdense + 4194304;       // 4 x 1048576 = 4194304 f
  float* xt     = abp + 4194304;          // 4194304 f (NHWC)
  float* xa     = xdir;                   // reuse (xdir dead after K3)

  ParamSrc ps;
  for (int i = 0; i < 18; i++) ps.p[i] = d_in[2 + i];

  k_detect<<<dim3(1), 256, 0, stream>>>((const unsigned short*)x, flag);
  k_convert<<<dim3(96, 24), 256, 0, stream>>>(ps, flag, cpar, wdefb, woffb,
                                              wg1b, wcrossb, woutb, cwT);
  k_xt<<<dim3(1024), 256, 0, stream>>>(x, flag, xt);
  k_coff_m<<<dim3(256, 4), 256, 0, stream>>>(x, flag, woffb, offp);
  k_omerge<<<dim3(288), 256, 0, stream>>>(offp, cb_off, offc);
  k_deform<<<dim3(512, 4), 256, 0, stream>>>(xt, offc, wdefb, xdir);
  k_cross<<<dim3(256, 2), 256, 0, stream>>>(xdir, x_prev, flag, wcrossb, xdense);
  k_g1_m<<<dim3(256, 4), 256, 0, stream>>>(xdense, wg1b, abp);
  k_attn<<<dim3(1024), 256, 0, stream>>>(abp, cb_g1, cg1_gam, cg1_bet, cg1_mea,
                                         cg1_var, cwT, cb_g2, xdense, xa);
  k_out<<<dim3(256, 2), 256, 0, stream>>>(xa, woutb, cb_out, co_gam, co_bet,
                                          co_mea, co_var, x, d_out, flag);
}

// Round 10
// 358.010 us; speedup vs baseline: 1.5090x; 1.0998x over previous
//
#include <hip/hip_runtime.h>
#include <hip/hip_bf16.h>

using bf16 = __hip_bfloat16;
typedef __attribute__((ext_vector_type(8))) short short8;
typedef __attribute__((ext_vector_type(4))) float f32x4;

__device__ __forceinline__ float b2f(bf16 v){ return __bfloat162float(v); }
__device__ __forceinline__ float sigf(float v){ return 1.f/(1.f + __expf(-v)); }
__device__ __forceinline__ float ldv(const float* p, int i){ return p[i]; }
__device__ __forceinline__ float ldv(const bf16* p, int i){ return b2f(p[i]); }
__device__ __forceinline__ void stv(float* p, int i, float v){ p[i] = v; }
__device__ __forceinline__ void stv(bf16* p, int i, float v){ p[i] = __float2bfloat16(v); }
__device__ __forceinline__ float bfe(short8 v, int j){
  unsigned short s = (unsigned short)v[j];
  return b2f(*(bf16*)&s);
}

// load 2 adjacent values as one instruction (8B f32 / 4B bf16)
__device__ __forceinline__ void ld2v(const float* p, float& a, float& b){
  float2 v = *(const float2*)p; a = v.x; b = v.y;
}
__device__ __forceinline__ void ld2v(const bf16* p, float& a, float& b){
  unsigned int u = *(const unsigned int*)p;
  unsigned short s0 = (unsigned short)(u & 0xFFFF), s1 = (unsigned short)(u >> 16);
  a = b2f(*(bf16*)&s0); b = b2f(*(bf16*)&s1);
}
// load 8 adjacent values, return 4 packed bf16-pairs
__device__ __forceinline__ void ld8(const bf16* s, unsigned int* pk){
  short8 v = *(const short8*)s;
  #pragma unroll
  for (int e = 0; e < 4; e++)
    pk[e] = (unsigned int)(unsigned short)v[2*e]
          | ((unsigned int)(unsigned short)v[2*e+1] << 16);
}
__device__ __forceinline__ void ld8(const float* s, unsigned int* pk){
  f32x4 a = *(const f32x4*)s, c = *(const f32x4*)(s + 4);
  float vals[8] = {a[0],a[1],a[2],a[3],c[0],c[1],c[2],c[3]};
  #pragma unroll
  for (int e = 0; e < 4; e++){
    bf16 h0 = __float2bfloat16(vals[2*e]), h1 = __float2bfloat16(vals[2*e+1]);
    pk[e] = (unsigned int)*(unsigned short*)&h0
          | ((unsigned int)*(unsigned short*)&h1 << 16);
  }
}

// ---------------------------------------------------------------------------
// K0: dtype detect. flag=1 => inputs are f32.
// ---------------------------------------------------------------------------
__global__ __launch_bounds__(256) void k_detect(const unsigned short* xs, int* flag){
  __shared__ int cnt;
  if (threadIdx.x == 0) cnt = 0;
  __syncthreads();
  int local = 0;
  for (int i = threadIdx.x; i < 16384; i += 256){
    if (((xs[i] >> 7) & 0xFF) == 0xFF) local++;
  }
  if (local) atomicAdd(&cnt, local);
  __syncthreads();
  if (threadIdx.x == 0) *flag = (cnt > 0) ? 1 : 0;
}

// ---------------------------------------------------------------------------
// K0b: canonicalize params. slots 0-17: fp32 in cpar; 18-22: bf16 weights
// (19/20 remapped tap-major); 23: w_g2 (slot 10) transposed. grid (96,24).
// ---------------------------------------------------------------------------
struct ParamSrc { const void* p[18]; };

__global__ __launch_bounds__(256) void k_convert(ParamSrc ps, const int* flagp,
    float* cpar, bf16* wdefb, bf16* woffb, bf16* wg1b, bf16* wcrossb, bf16* woutb,
    float* cwT){
  static constexpr int n[24]   = {41472,18,147456,131072,147456,64,64,64,64,64,
                                  16384,256,65536,256,256,256,256,256,
                                  147456,73728,147456,131072,65536,16384};
  static constexpr int off[18] = {0,41472,41504,188960,320032,467488,467552,467616,
                                  467680,467744,467808,484192,484448,549984,550240,
                                  550496,550752,551008};
  const int s = blockIdx.y;
  const bool f32 = (*flagp != 0);
  if (s == 23){
    for (int i = blockIdx.x * 256 + threadIdx.x; i < 16384; i += gridDim.x * 256){
      const int c = i >> 8, co = i & 255;
      if (f32) cwT[i] = ((const float*)ps.p[10])[co * 64 + c];
      else     cwT[i] = b2f(((const bf16*)ps.p[10])[co * 64 + c]);
    }
    return;
  }
  if (s >= 18){
    static constexpr int srcs[5] = {2, 0, 4, 3, 12};
    const int src_slot = srcs[s - 18];
    bf16* dst = (s == 18) ? wdefb : (s == 19) ? woffb : (s == 20) ? wg1b
              : (s == 21) ? wcrossb : woutb;
    const int nsrc = (s == 19) ? 41472 : n[s];
    const bool remap = (s == 19 || s == 20);
    for (int i = blockIdx.x * 256 + threadIdx.x; i < n[s]; i += gridDim.x * 256){
      int srcIdx = i;
      if (remap){
        const int co = i / 2304, rem = i % 2304;
        const int chunk = rem / 288, r2 = rem % 288;
        const int tap = r2 >> 5, cl = r2 & 31;
        srcIdx = co * 2304 + (chunk * 32 + cl) * 9 + tap;
      }
      if (f32){
        const float* src = (const float*)ps.p[src_slot];
        dst[i] = (srcIdx < nsrc) ? __float2bfloat16(src[srcIdx]) : __float2bfloat16(0.f);
      } else {
        const bf16* src = (const bf16*)ps.p[src_slot];
        dst[i] = (srcIdx < nsrc) ? src[srcIdx] : __float2bfloat16(0.f);
      }
    }
    return;
  }
  float* dst = cpar + off[s];
  if (f32){
    const float* src = (const float*)ps.p[s];
    for (int i = blockIdx.x * 256 + threadIdx.x; i < n[s]; i += gridDim.x * 256)
      dst[i] = src[i];
  } else {
    const bf16* src = (const bf16*)ps.p[s];
    for (int i = blockIdx.x * 256 + threadIdx.x; i < n[s]; i += gridDim.x * 256)
      dst[i] = b2f(src[i]);
  }
}

// ---------------------------------------------------------------------------
// K1b: NHWC staging for deform gather, now BF16: x_t[b][g][p=4096][cg=64].
// Row = 128B; one short8 load covers 8 channels.
// ---------------------------------------------------------------------------
template<typename T>
__device__ __forceinline__ void xt_body(const T* __restrict__ x, bf16* __restrict__ xt){
  __shared__ float lds[64][65];
  const int bx = blockIdx.x;
  const int b = bx >> 8, y = (bx >> 2) & 63, g = bx & 3;
  const int t = threadIdx.x;
  const int px = t & 63, cq = t >> 6;
  #pragma unroll
  for (int it = 0; it < 16; it++){
    const int ch = cq * 16 + it;
    lds[ch][px] = ldv(x, ((b * 256 + g * 64 + ch) * 64 + y) * 64 + px);
  }
  __syncthreads();
  const int ch = t & 63, pb = t >> 6;
  bf16* ob = xt + ((b * 4 + g) * 4096 + y * 64) * 64 + ch;
  #pragma unroll
  for (int i = 0; i < 16; i++){
    const int p = pb * 16 + i;
    ob[p * 64] = __float2bfloat16(lds[ch][p]);
  }
}

__global__ __launch_bounds__(256) void k_xt(const void* x, const int* flagp, bf16* xt){
  if (*flagp) xt_body((const float*)x, xt);
  else        xt_body((const bf16*)x, xt);
}

// ---------------------------------------------------------------------------
// conv3 RAW split-K, TILE-STAGED (unchanged from R9 — passing).
// ---------------------------------------------------------------------------
template<typename T, int COT>
__device__ __forceinline__ void conv3_raw(const T* __restrict__ xin,
    const bf16* __restrict__ wb, float* __restrict__ outp, int co_lim,
    unsigned short* xt16, int cc_begin){
  const int bx = blockIdx.x;
  const int b = bx >> 6, y = bx & 63;
  const int t = threadIdx.x;
  const int l = t & 63, w = t >> 6;
  const int lm = l & 15, lq = l >> 4;
  const int px = w * 16 + lm;
  f32x4 acc[COT];
  #pragma unroll
  for (int m = 0; m < COT; m++) acc[m] = (f32x4){0.f,0.f,0.f,0.f};

  #pragma unroll
  for (int ch_i = 0; ch_i < 2; ch_i++){
    const int cc = cc_begin + ch_i * 32;
    __syncthreads();
    if (t < 96){
      const int c = t / 3, r = t - c * 3;
      xt16[c * 210 + r * 70 + 3]  = 0;
      xt16[c * 210 + r * 70 + 68] = 0;
    }
    #pragma unroll
    for (int it = 0; it < 3; it++){
      const int u = t + it * 256;
      const int pb = u & 7;
      const int cr = u >> 3;
      const int c = cr / 3, r = cr - c * 3;
      const int yy = y + r - 1;
      const int px0 = pb * 8;
      unsigned int pk[4];
      if ((unsigned)yy < 64u){
        ld8(xin + (b * 256 + cc + c) * 4096 + yy * 64 + px0, pk);
      } else {
        pk[0] = pk[1] = pk[2] = pk[3] = 0;
      }
      unsigned int* dp = (unsigned int*)(xt16 + c * 210 + r * 70 + 4 + px0);
      dp[0] = pk[0]; dp[1] = pk[1]; dp[2] = pk[2]; dp[3] = pk[3];
    }
    __syncthreads();
    const int chunkG = cc >> 5;
    const unsigned short* bt = xt16 + 3 + px;
    #pragma unroll
    for (int tap = 0; tap < 9; tap++){
      const int ti = tap / 3, tj = tap - ti * 3;
      short8 bfr;
      #pragma unroll
      for (int j = 0; j < 8; j++)
        bfr[j] = (short)bt[(lq * 8 + j) * 210 + ti * 70 + tj];
      #pragma unroll
      for (int m = 0; m < COT; m++){
        const bf16* ap = wb + (m * 16 + lm) * 2304 + chunkG * 288 + tap * 32 + lq * 8;
        short8 afr = *(const short8*)ap;
        acc[m] = __builtin_amdgcn_mfma_f32_16x16x32_bf16(afr, bfr, acc[m], 0, 0, 0);
      }
    }
  }
  const int p = y * 64 + px;
  #pragma unroll
  for (int m = 0; m < COT; m++){
    #pragma unroll
    for (int r = 0; r < 4; r++){
      const int co = m * 16 + lq * 4 + r;
      if (co >= co_lim) continue;
      outp[(b * co_lim + co) * 4096 + p] = acc[m][r];
    }
  }
}

__global__ __launch_bounds__(256) void k_coff_m(const void* x, const int* flagp,
    const bf16* woffb, float* offp){
  __shared__ __align__(16) unsigned short xtile[32 * 210];
  float* op = offp + blockIdx.y * 294912;
  const int cc0 = blockIdx.y * 64;
  if (*flagp) conv3_raw<float, 2>((const float*)x, woffb, op, 18, xtile, cc0);
  else        conv3_raw<bf16, 2>((const bf16*)x, woffb, op, 18, xtile, cc0);
}

__global__ __launch_bounds__(256) void k_g1_m(const float* xdense,
    const bf16* wg1b, float* abp){
  __shared__ __align__(16) unsigned short xtile[32 * 210];
  float* op = abp + blockIdx.y * 1048576;
  conv3_raw<float, 4>(xdense, wg1b, op, 64, xtile, blockIdx.y * 64);
}

// ---------------------------------------------------------------------------
// K1c: merge 4 offset partials + bias -> offc.
// ---------------------------------------------------------------------------
__global__ __launch_bounds__(256) void k_omerge(const float* __restrict__ offp,
    const float* __restrict__ cb, float* __restrict__ offc){
  const int i4 = (blockIdx.x * 256 + threadIdx.x) * 4;
  constexpr int PS = 294912;
  f32x4 a = *(const f32x4*)(offp + i4);
  f32x4 b = *(const f32x4*)(offp + PS + i4);
  f32x4 c = *(const f32x4*)(offp + 2 * PS + i4);
  f32x4 d = *(const f32x4*)(offp + 3 * PS + i4);
  const int co = (i4 >> 12) % 18;
  const float bias = cb[co];
  f32x4 r;
  #pragma unroll
  for (int j = 0; j < 4; j++) r[j] = ((a[j] + b[j]) + c[j]) + d[j] + bias;
  *(f32x4*)(offc + i4) = r;
}

// ---------------------------------------------------------------------------
// K2: deformable conv — MERGED single pass, bf16 NHWC gather.
// Offsets/weights computed ONCE per (px,tap); each thread covers 8 channels
// per short8 corner load (4 loads/tap vs 8 f32x4 in the two-pass version).
// LDS cols [32 px][600] u16 (pitch 600: dword stride 300 = 12 mod 32 ->
// ~2-way MFMA reads; 16B-aligned rows). MFMA = verified R2 fused structure.
// ---------------------------------------------------------------------------
#define CROWM 600

__global__ __launch_bounds__(256) void k_deform(const bf16* __restrict__ xt,
    const float* __restrict__ offc, const bf16* __restrict__ wdefb,
    float* __restrict__ xdir){
  __shared__ __align__(16) unsigned short cols[32 * CROWM];
  const int g = blockIdx.y;
  const int q0 = blockIdx.x * 32;
  const int b = q0 >> 12, p0 = q0 & 4095;
  const int t = threadIdx.x;
  {
    const int pos = t & 31, u8 = t >> 5;
    const int c0 = u8 * 8;
    const int p = p0 + pos;
    const int y = p >> 6, xx = p & 63;
    const float* ob = offc + b * 18 * 4096 + p;
    const bf16* xg = xt + (b * 4 + g) * 4096 * 64;
    #pragma unroll
    for (int k = 0; k < 9; k++){
      float dy = ob[(2 * k) * 4096];
      float dx = ob[(2 * k + 1) * 4096];
      float py = (float)(y + k / 3 - 1) + dy;
      float px = (float)(xx + k % 3 - 1) + dx;
      float y0f = floorf(py), x0f = floorf(px);
      int y0 = (int)y0f, x0 = (int)x0f;
      float wy1 = py - y0f, wx1 = px - x0f;
      float wy0 = 1.f - wy1, wx0 = 1.f - wx1;
      bool vy0 = (unsigned)y0 < 64u, vy1 = (unsigned)(y0 + 1) < 64u;
      bool vx0 = (unsigned)x0 < 64u, vx1 = (unsigned)(x0 + 1) < 64u;
      float w00 = (vy0 && vx0) ? wy0 * wx0 : 0.f;
      float w01 = (vy0 && vx1) ? wy0 * wx1 : 0.f;
      float w10 = (vy1 && vx0) ? wy1 * wx0 : 0.f;
      float w11 = (vy1 && vx1) ? wy1 * wx1 : 0.f;
      int yc0 = min(max(y0, 0), 63), yc1 = min(max(y0 + 1, 0), 63);
      int xc0 = min(max(x0, 0), 63), xc1 = min(max(x0 + 1, 0), 63);
      int i00 = yc0 * 64 + xc0, i01 = yc0 * 64 + xc1;
      int i10 = yc1 * 64 + xc0, i11 = yc1 * 64 + xc1;
      short8 s00 = *(const short8*)(xg + i00 * 64 + c0);
      short8 s01 = *(const short8*)(xg + i01 * 64 + c0);
      short8 s10 = *(const short8*)(xg + i10 * 64 + c0);
      short8 s11 = *(const short8*)(xg + i11 * 64 + c0);
      #pragma unroll
      for (int j = 0; j < 8; j++){
        float val = w00 * bfe(s00, j) + w01 * bfe(s01, j)
                  + w10 * bfe(s10, j) + w11 * bfe(s11, j);
        bf16 hv = __float2bfloat16(val);
        cols[pos * CROWM + (c0 + j) * 9 + k] = *(unsigned short*)&hv;
      }
    }
  }
  __syncthreads();
  {
    const int w = t >> 6;
    const int l = t & 63;
    const int lrow = l & 15;
    const int lhi = l >> 4;
    f32x4 acc0 = {0.f, 0.f, 0.f, 0.f};
    f32x4 acc1 = {0.f, 0.f, 0.f, 0.f};
    const bf16* wr = wdefb + (g * 64 + w * 16 + lrow) * 576;
    const unsigned short* b0p = cols + lrow * CROWM;
    const unsigned short* b1p = cols + (16 + lrow) * CROWM;
    #pragma unroll 2
    for (int kk = 0; kk < 576; kk += 32){
      int ko = kk + lhi * 8;
      short8 a  = *(const short8*)(wr + ko);
      short8 b0 = *(const short8*)(b0p + ko);
      short8 b1 = *(const short8*)(b1p + ko);
      acc0 = __builtin_amdgcn_mfma_f32_16x16x32_bf16(a, b0, acc0, 0, 0, 0);
      acc1 = __builtin_amdgcn_mfma_f32_16x16x32_bf16(a, b1, acc1, 0, 0, 0);
    }
    const int co_base = g * 64 + w * 16 + lhi * 4;
    #pragma unroll
    for (int r = 0; r < 4; r++){
      float* xo = xdir + (b * 256 + co_base + r) * 4096 + p0 + lrow;
      xo[0]  = acc0[r];
      xo[16] = acc1[r];
    }
  }
}

// ---------------------------------------------------------------------------
// K3: 1x1 conv concat([x_dir, x_prev]) * w_cross (256x512) — MFMA.
// ---------------------------------------------------------------------------
template<typename T>
__device__ __forceinline__ void cross_mfma_body(const float* __restrict__ xdir,
    const T* __restrict__ xprev, const bf16* __restrict__ wb,
    float* __restrict__ xdense, unsigned short* cols){
  const int bx = blockIdx.x;
  const int b = bx >> 6, y = bx & 63;
  const int co0 = blockIdx.y * 128;
  const int t = threadIdx.x;
  const int l = t & 63, w = t >> 6;
  const int lm = l & 15, lq = l >> 4;
  const int pos2 = t & 31, cq = t >> 5;
  unsigned int* cols32 = (unsigned int*)cols;
  f32x4 acc[8];
  #pragma unroll
  for (int m = 0; m < 8; m++) acc[m] = (f32x4){0.f,0.f,0.f,0.f};

  for (int cc = 0; cc < 512; cc += 64){
    __syncthreads();
    #pragma unroll
    for (int c8 = 0; c8 < 8; c8++){
      const int cl = cq * 8 + c8;
      const int ci = cc + cl;
      float v0, v1;
      if (ci < 256) ld2v(xdir + (b * 256 + ci) * 4096 + y * 64 + 2 * pos2, v0, v1);
      else          ld2v(xprev + (b * 256 + (ci - 256)) * 4096 + y * 64 + 2 * pos2, v0, v1);
      bf16 h0 = __float2bfloat16(v0), h1 = __float2bfloat16(v1);
      unsigned int packed = (unsigned int)*(unsigned short*)&h0
                          | ((unsigned int)*(unsigned short*)&h1 << 16);
      cols32[cl * 34 + pos2] = packed;
    }
    __syncthreads();
    #pragma unroll
    for (int kk = 0; kk < 64; kk += 32){
      short8 bfr;
      #pragma unroll
      for (int j = 0; j < 8; j++)
        bfr[j] = (short)cols[(kk + lq * 8 + j) * 68 + w * 16 + lm];
      #pragma unroll
      for (int m = 0; m < 8; m++){
        const bf16* ap = wb + (co0 + m * 16 + lm) * 512 + cc + kk + lq * 8;
        short8 afr = *(const short8*)ap;
        acc[m] = __builtin_amdgcn_mfma_f32_16x16x32_bf16(afr, bfr, acc[m], 0, 0, 0);
      }
    }
  }
  const int p = y * 64 + w * 16 + lm;
  #pragma unroll
  for (int m = 0; m < 8; m++){
    #pragma unroll
    for (int r = 0; r < 4; r++){
      const int co = co0 + m * 16 + lq * 4 + r;
      xdense[(b * 256 + co) * 4096 + p] = acc[m][r];
    }
  }
}

__global__ __launch_bounds__(256) void k_cross(const float* xdir, const void* xprev,
    const int* flagp, const bf16* wcb, float* xdense){
  __shared__ __align__(16) unsigned short cols[64 * 68];
  if (*flagp) cross_mfma_body(xdir, (const float*)xprev, wcb, xdense, cols);
  else        cross_mfma_body(xdir, (const bf16*)xprev, wcb, xdense, cols);
}

// ---------------------------------------------------------------------------
// K5: attn (R8 structure, passing). grid (1024), 256 thr.
// ---------------------------------------------------------------------------
__global__ __launch_bounds__(256) void k_attn(const float* __restrict__ abp,
    const float* __restrict__ cb1, const float* __restrict__ gam,
    const float* __restrict__ bet, const float* __restrict__ mea,
    const float* __restrict__ var, const float* __restrict__ cwT,
    const float* __restrict__ cb2, const float* __restrict__ xdense,
    float* __restrict__ xa){
  __shared__ float a_s[64][17];
  const int bx = blockIdx.x;
  const int b = bx >> 8, pc = bx & 255;
  const int p0 = pc * 16;
  const int t = threadIdx.x;
  constexpr int PS = 1048576;
  {
    const int ch = t >> 2;
    const int px0 = (t & 3) * 4;
    const float inv = gam[ch] * rsqrtf(var[ch] + 1e-5f);
    const float sh  = bet[ch] - mea[ch] * inv;
    const float bias = cb1[ch];
    const int ai = (b * 64 + ch) * 4096 + p0 + px0;
    #pragma unroll
    for (int j = 0; j < 4; j++){
      float s = ((abp[ai + j] + abp[PS + ai + j]) + abp[2 * PS + ai + j])
              + abp[3 * PS + ai + j];
      s += bias;
      s = s * inv + sh;
      s = s * sigf(s);
      a_s[ch][px0 + j] = s;
    }
  }
  __syncthreads();
  const int co = t;
  float acc[16];
  #pragma unroll
  for (int i = 0; i < 16; i++) acc[i] = 0.f;
  for (int c = 0; c < 64; c++){
    const float wv = cwT[c * 256 + co];
    #pragma unroll
    for (int i = 0; i < 16; i++) acc[i] += wv * a_s[c][i];
  }
  const float bias2 = cb2[co];
  const int base = (b * 256 + co) * 4096 + p0;
  #pragma unroll
  for (int i = 0; i < 16; i++){
    float attn = sigf(acc[i] + bias2);
    xa[base + i] = xdense[base + i] * attn;
  }
}

// ---------------------------------------------------------------------------
// K6: 1x1 conv 256->256 + bias + BN + SiLU + residual — MFMA.
// ---------------------------------------------------------------------------
template<typename T>
__device__ __forceinline__ void out_mfma_body(const float* __restrict__ xa,
    const bf16* __restrict__ wb, const float* __restrict__ cbv,
    const float* __restrict__ gam, const float* __restrict__ bet,
    const float* __restrict__ mea, const float* __restrict__ var,
    const T* __restrict__ xres, T* __restrict__ outp, unsigned short* cols){
  const int bx = blockIdx.x;
  const int b = bx >> 6, y = bx & 63;
  const int co0 = blockIdx.y * 128;
  const int t = threadIdx.x;
  const int l = t & 63, w = t >> 6;
  const int lm = l & 15, lq = l >> 4;
  const int pos2 = t & 31, cq = t >> 5;
  unsigned int* cols32 = (unsigned int*)cols;
  f32x4 acc[8];
  #pragma unroll
  for (int m = 0; m < 8; m++) acc[m] = (f32x4){0.f,0.f,0.f,0.f};

  for (int cc = 0; cc < 256; cc += 64){
    __syncthreads();
    #pragma unroll
    for (int c8 = 0; c8 < 8; c8++){
      const int cl = cq * 8 + c8;
      const int ci = cc + cl;
      float v0, v1;
      ld2v(xa + (b * 256 + ci) * 4096 + y * 64 + 2 * pos2, v0, v1);
      bf16 h0 = __float2bfloat16(v0), h1 = __float2bfloat16(v1);
      unsigned int packed = (unsigned int)*(unsigned short*)&h0
                          | ((unsigned int)*(unsigned short*)&h1 << 16);
      cols32[cl * 34 + pos2] = packed;
    }
    __syncthreads();
    #pragma unroll
    for (int kk = 0; kk < 64; kk += 32){
      short8 bfr;
      #pragma unroll
      for (int j = 0; j < 8; j++)
        bfr[j] = (short)cols[(kk + lq * 8 + j) * 68 + w * 16 + lm];
      #pragma unroll
      for (int m = 0; m < 8; m++){
        const bf16* ap = wb + (co0 + m * 16 + lm) * 256 + cc + kk + lq * 8;
        short8 afr = *(const short8*)ap;
        acc[m] = __builtin_amdgcn_mfma_f32_16x16x32_bf16(afr, bfr, acc[m], 0, 0, 0);
      }
    }
  }
  const int p = y * 64 + w * 16 + lm;
  #pragma unroll
  for (int m = 0; m < 8; m++){
    #pragma unroll
    for (int r = 0; r < 4; r++){
      const int co = co0 + m * 16 + lq * 4 + r;
      float inv = gam[co] * rsqrtf(var[co] + 1e-5f);
      float v = acc[m][r] + cbv[co];
      v = v * inv + (bet[co] - mea[co] * inv);
      v = v * sigf(v);
      const int idx = (b * 256 + co) * 4096 + p;
      stv(outp, idx, v + ldv(xres, idx));
    }
  }
}

__global__ __launch_bounds__(256) void k_out(const float* xa, const bf16* wob,
    const float* cb, const float* gam, const float* bet, const float* mea,
    const float* var, const void* xres, void* out, const int* flagp){
  __shared__ __align__(16) unsigned short cols[64 * 68];
  if (*flagp) out_mfma_body(xa, wob, cb, gam, bet, mea, var,
                            (const float*)xres, (float*)out, cols);
  else        out_mfma_body(xa, wob, cb, gam, bet, mea, var,
                            (const bf16*)xres, (bf16*)out, cols);
}

// ---------------------------------------------------------------------------
extern "C" void kernel_launch(void* const* d_in, const int* in_sizes, int n_in,
                              void* d_out, int out_size, void* d_ws, size_t ws_size,
                              hipStream_t stream) {
  const void* x      = d_in[0];
  const void* x_prev = d_in[1];

  float* ws   = (float*)d_ws;
  int*   flag = (int*)ws;                 // ws[0..15] reserved
  float* cpar = ws + 16;                  // canonical fp32 params (551264 f)
  float* cb_off   = cpar + 41472;
  float* cb_g1    = cpar + 467488;
  float* cg1_gam  = cpar + 467552;
  float* cg1_bet  = cpar + 467616;
  float* cg1_mea  = cpar + 467680;
  float* cg1_var  = cpar + 467744;
  float* cb_g2    = cpar + 484192;
  float* cb_out   = cpar + 549984;
  float* co_gam   = cpar + 550240;
  float* co_bet   = cpar + 550496;
  float* co_mea   = cpar + 550752;
  float* co_var   = cpar + 551008;

  float* cwT     = ws + 16 + 551264;                // 16384 f (w_g2 transposed)
  bf16*  wdefb   = (bf16*)(ws + 567664);            // 73728 f
  bf16*  woffb   = (bf16*)(ws + 641392);            // 36864 f
  bf16*  wg1b    = (bf16*)(ws + 678256);            // 73728 f
  bf16*  wcrossb = (bf16*)(ws + 751984);            // 65536 f
  bf16*  woutb   = (bf16*)(ws + 817520);            // 32768 f
  float* base    = ws + 850288;
  float* offp   = base;                   // 4 x 294912  = 1179648 f
  float* offc   = offp + 1179648;         // 294912 f
  float* xdir   = offc + 294912;          // 4194304 f
  float* xdense = xdir + 4194304;         // 4194304 f
  float* abp    = xdense + 4194304;       // 4 x 1048576 = 4194304 f
  bf16*  xtb    = (bf16*)(abp + 4194304); // 16777216 hw = 8388608 f (NHWC bf16)
  float* xa     = xdir;                   // reuse (xdir dead after K3)

  ParamSrc ps;
  for (int i = 0; i < 18; i++) ps.p[i] = d_in[2 + i];

  k_detect<<<dim3(1), 256, 0, stream>>>((const unsigned short*)x, flag);
  k_convert<<<dim3(96, 24), 256, 0, stream>>>(ps, flag, cpar, wdefb, woffb,
                                              wg1b, wcrossb, woutb, cwT);
  k_xt<<<dim3(1024), 256, 0, stream>>>(x, flag, xtb);
  k_coff_m<<<dim3(256, 4), 256, 0, stream>>>(x, flag, woffb, offp);
  k_omerge<<<dim3(288), 256, 0, stream>>>(offp, cb_off, offc);
  k_deform<<<dim3(512, 4), 256, 0, stream>>>(xtb, offc, wdefb, xdir);
  k_cross<<<dim3(256, 2), 256, 0, stream>>>(xdir, x_prev, flag, wcrossb, xdense);
  k_g1_m<<<dim3(256, 4), 256, 0, stream>>>(xdense, wg1b, abp);
  k_attn<<<dim3(1024), 256, 0, stream>>>(abp, cb_g1, cg1_gam, cg1_bet, cg1_mea,
                                         cg1_var, cwT, cb_g2, xdense, xa);
  k_out<<<dim3(256, 2), 256, 0, stream>>>(xa, woutb, cb_out, co_gam, co_bet,
                                          co_mea, co_var, x, d_out, flag);
}

// Round 11
// 349.861 us; speedup vs baseline: 1.5441x; 1.0233x over previous
//
#include <hip/hip_runtime.h>
#include <hip/hip_bf16.h>

using bf16 = __hip_bfloat16;
typedef __attribute__((ext_vector_type(8))) short short8;
typedef __attribute__((ext_vector_type(4))) float f32x4;

__device__ __forceinline__ float b2f(bf16 v){ return __bfloat162float(v); }
__device__ __forceinline__ float sigf(float v){ return 1.f/(1.f + __expf(-v)); }
__device__ __forceinline__ float ldv(const float* p, int i){ return p[i]; }
__device__ __forceinline__ float ldv(const bf16* p, int i){ return b2f(p[i]); }
__device__ __forceinline__ void stv(float* p, int i, float v){ p[i] = v; }
__device__ __forceinline__ void stv(bf16* p, int i, float v){ p[i] = __float2bfloat16(v); }
__device__ __forceinline__ float bfe(short8 v, int j){
  unsigned short s = (unsigned short)v[j];
  return b2f(*(bf16*)&s);
}

// load 2 adjacent values as one instruction (8B f32 / 4B bf16)
__device__ __forceinline__ void ld2v(const float* p, float& a, float& b){
  float2 v = *(const float2*)p; a = v.x; b = v.y;
}
__device__ __forceinline__ void ld2v(const bf16* p, float& a, float& b){
  unsigned int u = *(const unsigned int*)p;
  unsigned short s0 = (unsigned short)(u & 0xFFFF), s1 = (unsigned short)(u >> 16);
  a = b2f(*(bf16*)&s0); b = b2f(*(bf16*)&s1);
}
// load 8 adjacent values, return 4 packed bf16-pairs
__device__ __forceinline__ void ld8(const bf16* s, unsigned int* pk){
  short8 v = *(const short8*)s;
  #pragma unroll
  for (int e = 0; e < 4; e++)
    pk[e] = (unsigned int)(unsigned short)v[2*e]
          | ((unsigned int)(unsigned short)v[2*e+1] << 16);
}
__device__ __forceinline__ void ld8(const float* s, unsigned int* pk){
  f32x4 a = *(const f32x4*)s, c = *(const f32x4*)(s + 4);
  float vals[8] = {a[0],a[1],a[2],a[3],c[0],c[1],c[2],c[3]};
  #pragma unroll
  for (int e = 0; e < 4; e++){
    bf16 h0 = __float2bfloat16(vals[2*e]), h1 = __float2bfloat16(vals[2*e+1]);
    pk[e] = (unsigned int)*(unsigned short*)&h0
          | ((unsigned int)*(unsigned short*)&h1 << 16);
  }
}

// ---------------------------------------------------------------------------
// K0: dtype detect. flag=1 => inputs are f32.
// ---------------------------------------------------------------------------
__global__ __launch_bounds__(256) void k_detect(const unsigned short* xs, int* flag){
  __shared__ int cnt;
  if (threadIdx.x == 0) cnt = 0;
  __syncthreads();
  int local = 0;
  for (int i = threadIdx.x; i < 16384; i += 256){
    if (((xs[i] >> 7) & 0xFF) == 0xFF) local++;
  }
  if (local) atomicAdd(&cnt, local);
  __syncthreads();
  if (threadIdx.x == 0) *flag = (cnt > 0) ? 1 : 0;
}

// ---------------------------------------------------------------------------
// K0b: canonicalize params. slots 0-17: fp32 in cpar; 18-22: bf16 weights
// (19/20 remapped tap-major); 23: w_g2 (slot 10) transposed. grid (96,24).
// ---------------------------------------------------------------------------
struct ParamSrc { const void* p[18]; };

__global__ __launch_bounds__(256) void k_convert(ParamSrc ps, const int* flagp,
    float* cpar, bf16* wdefb, bf16* woffb, bf16* wg1b, bf16* wcrossb, bf16* woutb,
    float* cwT){
  static constexpr int n[24]   = {41472,18,147456,131072,147456,64,64,64,64,64,
                                  16384,256,65536,256,256,256,256,256,
                                  147456,73728,147456,131072,65536,16384};
  static constexpr int off[18] = {0,41472,41504,188960,320032,467488,467552,467616,
                                  467680,467744,467808,484192,484448,549984,550240,
                                  550496,550752,551008};
  const int s = blockIdx.y;
  const bool f32 = (*flagp != 0);
  if (s == 23){
    for (int i = blockIdx.x * 256 + threadIdx.x; i < 16384; i += gridDim.x * 256){
      const int c = i >> 8, co = i & 255;
      if (f32) cwT[i] = ((const float*)ps.p[10])[co * 64 + c];
      else     cwT[i] = b2f(((const bf16*)ps.p[10])[co * 64 + c]);
    }
    return;
  }
  if (s >= 18){
    static constexpr int srcs[5] = {2, 0, 4, 3, 12};
    const int src_slot = srcs[s - 18];
    bf16* dst = (s == 18) ? wdefb : (s == 19) ? woffb : (s == 20) ? wg1b
              : (s == 21) ? wcrossb : woutb;
    const int nsrc = (s == 19) ? 41472 : n[s];
    const bool remap = (s == 19 || s == 20);
    for (int i = blockIdx.x * 256 + threadIdx.x; i < n[s]; i += gridDim.x * 256){
      int srcIdx = i;
      if (remap){
        const int co = i / 2304, rem = i % 2304;
        const int chunk = rem / 288, r2 = rem % 288;
        const int tap = r2 >> 5, cl = r2 & 31;
        srcIdx = co * 2304 + (chunk * 32 + cl) * 9 + tap;
      }
      if (f32){
        const float* src = (const float*)ps.p[src_slot];
        dst[i] = (srcIdx < nsrc) ? __float2bfloat16(src[srcIdx]) : __float2bfloat16(0.f);
      } else {
        const bf16* src = (const bf16*)ps.p[src_slot];
        dst[i] = (srcIdx < nsrc) ? src[srcIdx] : __float2bfloat16(0.f);
      }
    }
    return;
  }
  float* dst = cpar + off[s];
  if (f32){
    const float* src = (const float*)ps.p[s];
    for (int i = blockIdx.x * 256 + threadIdx.x; i < n[s]; i += gridDim.x * 256)
      dst[i] = src[i];
  } else {
    const bf16* src = (const bf16*)ps.p[s];
    for (int i = blockIdx.x * 256 + threadIdx.x; i < n[s]; i += gridDim.x * 256)
      dst[i] = b2f(src[i]);
  }
}

// ---------------------------------------------------------------------------
// K1b: NHWC bf16 staging for deform gather: x_t[b][g][p=4096][cg=64].
// ---------------------------------------------------------------------------
template<typename T>
__device__ __forceinline__ void xt_body(const T* __restrict__ x, bf16* __restrict__ xt){
  __shared__ float lds[64][65];
  const int bx = blockIdx.x;
  const int b = bx >> 8, y = (bx >> 2) & 63, g = bx & 3;
  const int t = threadIdx.x;
  const int px = t & 63, cq = t >> 6;
  #pragma unroll
  for (int it = 0; it < 16; it++){
    const int ch = cq * 16 + it;
    lds[ch][px] = ldv(x, ((b * 256 + g * 64 + ch) * 64 + y) * 64 + px);
  }
  __syncthreads();
  const int ch = t & 63, pb = t >> 6;
  bf16* ob = xt + ((b * 4 + g) * 4096 + y * 64) * 64 + ch;
  #pragma unroll
  for (int i = 0; i < 16; i++){
    const int p = pb * 16 + i;
    ob[p * 64] = __float2bfloat16(lds[ch][p]);
  }
}

__global__ __launch_bounds__(256) void k_xt(const void* x, const int* flagp, bf16* xt){
  if (*flagp) xt_body((const float*)x, xt);
  else        xt_body((const bf16*)x, xt);
}

// ---------------------------------------------------------------------------
// conv3 RAW split-K, TILE-STAGED (R9 structure — passing).
// ---------------------------------------------------------------------------
template<typename T, int COT>
__device__ __forceinline__ void conv3_raw(const T* __restrict__ xin,
    const bf16* __restrict__ wb, float* __restrict__ outp, int co_lim,
    unsigned short* xt16, int cc_begin){
  const int bx = blockIdx.x;
  const int b = bx >> 6, y = bx & 63;
  const int t = threadIdx.x;
  const int l = t & 63, w = t >> 6;
  const int lm = l & 15, lq = l >> 4;
  const int px = w * 16 + lm;
  f32x4 acc[COT];
  #pragma unroll
  for (int m = 0; m < COT; m++) acc[m] = (f32x4){0.f,0.f,0.f,0.f};

  #pragma unroll
  for (int ch_i = 0; ch_i < 2; ch_i++){
    const int cc = cc_begin + ch_i * 32;
    __syncthreads();
    if (t < 96){
      const int c = t / 3, r = t - c * 3;
      xt16[c * 210 + r * 70 + 3]  = 0;
      xt16[c * 210 + r * 70 + 68] = 0;
    }
    #pragma unroll
    for (int it = 0; it < 3; it++){
      const int u = t + it * 256;
      const int pb = u & 7;
      const int cr = u >> 3;
      const int c = cr / 3, r = cr - c * 3;
      const int yy = y + r - 1;
      const int px0 = pb * 8;
      unsigned int pk[4];
      if ((unsigned)yy < 64u){
        ld8(xin + (b * 256 + cc + c) * 4096 + yy * 64 + px0, pk);
      } else {
        pk[0] = pk[1] = pk[2] = pk[3] = 0;
      }
      unsigned int* dp = (unsigned int*)(xt16 + c * 210 + r * 70 + 4 + px0);
      dp[0] = pk[0]; dp[1] = pk[1]; dp[2] = pk[2]; dp[3] = pk[3];
    }
    __syncthreads();
    const int chunkG = cc >> 5;
    const unsigned short* bt = xt16 + 3 + px;
    #pragma unroll
    for (int tap = 0; tap < 9; tap++){
      const int ti = tap / 3, tj = tap - ti * 3;
      short8 bfr;
      #pragma unroll
      for (int j = 0; j < 8; j++)
        bfr[j] = (short)bt[(lq * 8 + j) * 210 + ti * 70 + tj];
      #pragma unroll
      for (int m = 0; m < COT; m++){
        const bf16* ap = wb + (m * 16 + lm) * 2304 + chunkG * 288 + tap * 32 + lq * 8;
        short8 afr = *(const short8*)ap;
        acc[m] = __builtin_amdgcn_mfma_f32_16x16x32_bf16(afr, bfr, acc[m], 0, 0, 0);
      }
    }
  }
  const int p = y * 64 + px;
  #pragma unroll
  for (int m = 0; m < COT; m++){
    #pragma unroll
    for (int r = 0; r < 4; r++){
      const int co = m * 16 + lq * 4 + r;
      if (co >= co_lim) continue;
      outp[(b * co_lim + co) * 4096 + p] = acc[m][r];
    }
  }
}

__global__ __launch_bounds__(256) void k_coff_m(const void* x, const int* flagp,
    const bf16* woffb, float* offp){
  __shared__ __align__(16) unsigned short xtile[32 * 210];
  float* op = offp + blockIdx.y * 294912;
  const int cc0 = blockIdx.y * 64;
  if (*flagp) conv3_raw<float, 2>((const float*)x, woffb, op, 18, xtile, cc0);
  else        conv3_raw<bf16, 2>((const bf16*)x, woffb, op, 18, xtile, cc0);
}

__global__ __launch_bounds__(256) void k_g1_m(const bf16* xdense,
    const bf16* wg1b, float* abp){
  __shared__ __align__(16) unsigned short xtile[32 * 210];
  float* op = abp + blockIdx.y * 1048576;
  conv3_raw<bf16, 4>(xdense, wg1b, op, 64, xtile, blockIdx.y * 64);
}

// ---------------------------------------------------------------------------
// K1c: merge 4 offset partials + bias -> offc.
// ---------------------------------------------------------------------------
__global__ __launch_bounds__(256) void k_omerge(const float* __restrict__ offp,
    const float* __restrict__ cb, float* __restrict__ offc){
  const int i4 = (blockIdx.x * 256 + threadIdx.x) * 4;
  constexpr int PS = 294912;
  f32x4 a = *(const f32x4*)(offp + i4);
  f32x4 b = *(const f32x4*)(offp + PS + i4);
  f32x4 c = *(const f32x4*)(offp + 2 * PS + i4);
  f32x4 d = *(const f32x4*)(offp + 3 * PS + i4);
  const int co = (i4 >> 12) % 18;
  const float bias = cb[co];
  f32x4 r;
  #pragma unroll
  for (int j = 0; j < 4; j++) r[j] = ((a[j] + b[j]) + c[j]) + d[j] + bias;
  *(f32x4*)(offc + i4) = r;
}

// ---------------------------------------------------------------------------
// K2: deformable conv — merged single-pass bf16 NHWC gather (R10 structure).
// R11: epilogue stores xdir as BF16 (bit-identical downstream: k_cross
// staged-rounds these exact values anyway).
// ---------------------------------------------------------------------------
#define CROWM 600

__global__ __launch_bounds__(256) void k_deform(const bf16* __restrict__ xt,
    const float* __restrict__ offc, const bf16* __restrict__ wdefb,
    bf16* __restrict__ xdir){
  __shared__ __align__(16) unsigned short cols[32 * CROWM];
  const int g = blockIdx.y;
  const int q0 = blockIdx.x * 32;
  const int b = q0 >> 12, p0 = q0 & 4095;
  const int t = threadIdx.x;
  {
    const int pos = t & 31, u8 = t >> 5;
    const int c0 = u8 * 8;
    const int p = p0 + pos;
    const int y = p >> 6, xx = p & 63;
    const float* ob = offc + b * 18 * 4096 + p;
    const bf16* xg = xt + (b * 4 + g) * 4096 * 64;
    #pragma unroll
    for (int k = 0; k < 9; k++){
      float dy = ob[(2 * k) * 4096];
      float dx = ob[(2 * k + 1) * 4096];
      float py = (float)(y + k / 3 - 1) + dy;
      float px = (float)(xx + k % 3 - 1) + dx;
      float y0f = floorf(py), x0f = floorf(px);
      int y0 = (int)y0f, x0 = (int)x0f;
      float wy1 = py - y0f, wx1 = px - x0f;
      float wy0 = 1.f - wy1, wx0 = 1.f - wx1;
      bool vy0 = (unsigned)y0 < 64u, vy1 = (unsigned)(y0 + 1) < 64u;
      bool vx0 = (unsigned)x0 < 64u, vx1 = (unsigned)(x0 + 1) < 64u;
      float w00 = (vy0 && vx0) ? wy0 * wx0 : 0.f;
      float w01 = (vy0 && vx1) ? wy0 * wx1 : 0.f;
      float w10 = (vy1 && vx0) ? wy1 * wx0 : 0.f;
      float w11 = (vy1 && vx1) ? wy1 * wx1 : 0.f;
      int yc0 = min(max(y0, 0), 63), yc1 = min(max(y0 + 1, 0), 63);
      int xc0 = min(max(x0, 0), 63), xc1 = min(max(x0 + 1, 0), 63);
      int i00 = yc0 * 64 + xc0, i01 = yc0 * 64 + xc1;
      int i10 = yc1 * 64 + xc0, i11 = yc1 * 64 + xc1;
      short8 s00 = *(const short8*)(xg + i00 * 64 + c0);
      short8 s01 = *(const short8*)(xg + i01 * 64 + c0);
      short8 s10 = *(const short8*)(xg + i10 * 64 + c0);
      short8 s11 = *(const short8*)(xg + i11 * 64 + c0);
      #pragma unroll
      for (int j = 0; j < 8; j++){
        float val = w00 * bfe(s00, j) + w01 * bfe(s01, j)
                  + w10 * bfe(s10, j) + w11 * bfe(s11, j);
        bf16 hv = __float2bfloat16(val);
        cols[pos * CROWM + (c0 + j) * 9 + k] = *(unsigned short*)&hv;
      }
    }
  }
  __syncthreads();
  {
    const int w = t >> 6;
    const int l = t & 63;
    const int lrow = l & 15;
    const int lhi = l >> 4;
    f32x4 acc0 = {0.f, 0.f, 0.f, 0.f};
    f32x4 acc1 = {0.f, 0.f, 0.f, 0.f};
    const bf16* wr = wdefb + (g * 64 + w * 16 + lrow) * 576;
    const unsigned short* b0p = cols + lrow * CROWM;
    const unsigned short* b1p = cols + (16 + lrow) * CROWM;
    #pragma unroll 2
    for (int kk = 0; kk < 576; kk += 32){
      int ko = kk + lhi * 8;
      short8 a  = *(const short8*)(wr + ko);
      short8 b0 = *(const short8*)(b0p + ko);
      short8 b1 = *(const short8*)(b1p + ko);
      acc0 = __builtin_amdgcn_mfma_f32_16x16x32_bf16(a, b0, acc0, 0, 0, 0);
      acc1 = __builtin_amdgcn_mfma_f32_16x16x32_bf16(a, b1, acc1, 0, 0, 0);
    }
    const int co_base = g * 64 + w * 16 + lhi * 4;
    #pragma unroll
    for (int r = 0; r < 4; r++){
      bf16* xo = xdir + (b * 256 + co_base + r) * 4096 + p0 + lrow;
      xo[0]  = __float2bfloat16(acc0[r]);
      xo[16] = __float2bfloat16(acc1[r]);
    }
  }
}

// ---------------------------------------------------------------------------
// K3: 1x1 conv concat([x_dir, x_prev]) * w_cross — MFMA. xdir now bf16;
// epilogue stores xdense as bf16.
// ---------------------------------------------------------------------------
template<typename T>
__device__ __forceinline__ void cross_mfma_body(const bf16* __restrict__ xdir,
    const T* __restrict__ xprev, const bf16* __restrict__ wb,
    bf16* __restrict__ xdense, unsigned short* cols){
  const int bx = blockIdx.x;
  const int b = bx >> 6, y = bx & 63;
  const int co0 = blockIdx.y * 128;
  const int t = threadIdx.x;
  const int l = t & 63, w = t >> 6;
  const int lm = l & 15, lq = l >> 4;
  const int pos2 = t & 31, cq = t >> 5;
  unsigned int* cols32 = (unsigned int*)cols;
  f32x4 acc[8];
  #pragma unroll
  for (int m = 0; m < 8; m++) acc[m] = (f32x4){0.f,0.f,0.f,0.f};

  for (int cc = 0; cc < 512; cc += 64){
    __syncthreads();
    #pragma unroll
    for (int c8 = 0; c8 < 8; c8++){
      const int cl = cq * 8 + c8;
      const int ci = cc + cl;
      float v0, v1;
      if (ci < 256) ld2v(xdir + (b * 256 + ci) * 4096 + y * 64 + 2 * pos2, v0, v1);
      else          ld2v(xprev + (b * 256 + (ci - 256)) * 4096 + y * 64 + 2 * pos2, v0, v1);
      bf16 h0 = __float2bfloat16(v0), h1 = __float2bfloat16(v1);
      unsigned int packed = (unsigned int)*(unsigned short*)&h0
                          | ((unsigned int)*(unsigned short*)&h1 << 16);
      cols32[cl * 34 + pos2] = packed;
    }
    __syncthreads();
    #pragma unroll
    for (int kk = 0; kk < 64; kk += 32){
      short8 bfr;
      #pragma unroll
      for (int j = 0; j < 8; j++)
        bfr[j] = (short)cols[(kk + lq * 8 + j) * 68 + w * 16 + lm];
      #pragma unroll
      for (int m = 0; m < 8; m++){
        const bf16* ap = wb + (co0 + m * 16 + lm) * 512 + cc + kk + lq * 8;
        short8 afr = *(const short8*)ap;
        acc[m] = __builtin_amdgcn_mfma_f32_16x16x32_bf16(afr, bfr, acc[m], 0, 0, 0);
      }
    }
  }
  const int p = y * 64 + w * 16 + lm;
  #pragma unroll
  for (int m = 0; m < 8; m++){
    #pragma unroll
    for (int r = 0; r < 4; r++){
      const int co = co0 + m * 16 + lq * 4 + r;
      xdense[(b * 256 + co) * 4096 + p] = __float2bfloat16(acc[m][r]);
    }
  }
}

__global__ __launch_bounds__(256) void k_cross(const bf16* xdir, const void* xprev,
    const int* flagp, const bf16* wcb, bf16* xdense){
  __shared__ __align__(16) unsigned short cols[64 * 68];
  if (*flagp) cross_mfma_body(xdir, (const float*)xprev, wcb, xdense, cols);
  else        cross_mfma_body(xdir, (const bf16*)xprev, wcb, xdense, cols);
}

// ---------------------------------------------------------------------------
// K5: attn (R8 structure). xdense read bf16; xa written bf16.
// ---------------------------------------------------------------------------
__global__ __launch_bounds__(256) void k_attn(const float* __restrict__ abp,
    const float* __restrict__ cb1, const float* __restrict__ gam,
    const float* __restrict__ bet, const float* __restrict__ mea,
    const float* __restrict__ var, const float* __restrict__ cwT,
    const float* __restrict__ cb2, const bf16* __restrict__ xdense,
    bf16* __restrict__ xa){
  __shared__ float a_s[64][17];
  const int bx = blockIdx.x;
  const int b = bx >> 8, pc = bx & 255;
  const int p0 = pc * 16;
  const int t = threadIdx.x;
  constexpr int PS = 1048576;
  {
    const int ch = t >> 2;
    const int px0 = (t & 3) * 4;
    const float inv = gam[ch] * rsqrtf(var[ch] + 1e-5f);
    const float sh  = bet[ch] - mea[ch] * inv;
    const float bias = cb1[ch];
    const int ai = (b * 64 + ch) * 4096 + p0 + px0;
    #pragma unroll
    for (int j = 0; j < 4; j++){
      float s = ((abp[ai + j] + abp[PS + ai + j]) + abp[2 * PS + ai + j])
              + abp[3 * PS + ai + j];
      s += bias;
      s = s * inv + sh;
      s = s * sigf(s);
      a_s[ch][px0 + j] = s;
    }
  }
  __syncthreads();
  const int co = t;
  float acc[16];
  #pragma unroll
  for (int i = 0; i < 16; i++) acc[i] = 0.f;
  for (int c = 0; c < 64; c++){
    const float wv = cwT[c * 256 + co];
    #pragma unroll
    for (int i = 0; i < 16; i++) acc[i] += wv * a_s[c][i];
  }
  const float bias2 = cb2[co];
  const int base = (b * 256 + co) * 4096 + p0;
  #pragma unroll
  for (int i = 0; i < 16; i++){
    float attn = sigf(acc[i] + bias2);
    xa[base + i] = __float2bfloat16(b2f(xdense[base + i]) * attn);
  }
}

// ---------------------------------------------------------------------------
// K6: 1x1 conv 256->256 + bias + BN + SiLU + residual — MFMA. xa now bf16.
// ---------------------------------------------------------------------------
template<typename T>
__device__ __forceinline__ void out_mfma_body(const bf16* __restrict__ xa,
    const bf16* __restrict__ wb, const float* __restrict__ cbv,
    const float* __restrict__ gam, const float* __restrict__ bet,
    const float* __restrict__ mea, const float* __restrict__ var,
    const T* __restrict__ xres, T* __restrict__ outp, unsigned short* cols){
  const int bx = blockIdx.x;
  const int b = bx >> 6, y = bx & 63;
  const int co0 = blockIdx.y * 128;
  const int t = threadIdx.x;
  const int l = t & 63, w = t >> 6;
  const int lm = l & 15, lq = l >> 4;
  const int pos2 = t & 31, cq = t >> 5;
  unsigned int* cols32 = (unsigned int*)cols;
  f32x4 acc[8];
  #pragma unroll
  for (int m = 0; m < 8; m++) acc[m] = (f32x4){0.f,0.f,0.f,0.f};

  for (int cc = 0; cc < 256; cc += 64){
    __syncthreads();
    #pragma unroll
    for (int c8 = 0; c8 < 8; c8++){
      const int cl = cq * 8 + c8;
      const int ci = cc + cl;
      // xa is bf16: copy 2 px (4B) directly, values already rounded
      const unsigned int u = *(const unsigned int*)(xa + (b * 256 + ci) * 4096
                                                    + y * 64 + 2 * pos2);
      cols32[cl * 34 + pos2] = u;
    }
    __syncthreads();
    #pragma unroll
    for (int kk = 0; kk < 64; kk += 32){
      short8 bfr;
      #pragma unroll
      for (int j = 0; j < 8; j++)
        bfr[j] = (short)cols[(kk + lq * 8 + j) * 68 + w * 16 + lm];
      #pragma unroll
      for (int m = 0; m < 8; m++){
        const bf16* ap = wb + (co0 + m * 16 + lm) * 256 + cc + kk + lq * 8;
        short8 afr = *(const short8*)ap;
        acc[m] = __builtin_amdgcn_mfma_f32_16x16x32_bf16(afr, bfr, acc[m], 0, 0, 0);
      }
    }
  }
  const int p = y * 64 + w * 16 + lm;
  #pragma unroll
  for (int m = 0; m < 8; m++){
    #pragma unroll
    for (int r = 0; r < 4; r++){
      const int co = co0 + m * 16 + lq * 4 + r;
      float inv = gam[co] * rsqrtf(var[co] + 1e-5f);
      float v = acc[m][r] + cbv[co];
      v = v * inv + (bet[co] - mea[co] * inv);
      v = v * sigf(v);
      const int idx = (b * 256 + co) * 4096 + p;
      stv(outp, idx, v + ldv(xres, idx));
    }
  }
}

__global__ __launch_bounds__(256) void k_out(const bf16* xa, const bf16* wob,
    const float* cb, const float* gam, const float* bet, const float* mea,
    const float* var, const void* xres, void* out, const int* flagp){
  __shared__ __align__(16) unsigned short cols[64 * 68];
  if (*flagp) out_mfma_body(xa, wob, cb, gam, bet, mea, var,
                            (const float*)xres, (float*)out, cols);
  else        out_mfma_body(xa, wob, cb, gam, bet, mea, var,
                            (const bf16*)xres, (bf16*)out, cols);
}

// ---------------------------------------------------------------------------
extern "C" void kernel_launch(void* const* d_in, const int* in_sizes, int n_in,
                              void* d_out, int out_size, void* d_ws, size_t ws_size,
                              hipStream_t stream) {
  const void* x      = d_in[0];
  const void* x_prev = d_in[1];

  float* ws   = (float*)d_ws;
  int*   flag = (int*)ws;                 // ws[0..15] reserved
  float* cpar = ws + 16;                  // canonical fp32 params (551264 f)
  float* cb_off   = cpar + 41472;
  float* cb_g1    = cpar + 467488;
  float* cg1_gam  = cpar + 467552;
  float* cg1_bet  = cpar + 467616;
  float* cg1_mea  = cpar + 467680;
  float* cg1_var  = cpar + 467744;
  float* cb_g2    = cpar + 484192;
  float* cb_out   = cpar + 549984;
  float* co_gam   = cpar + 550240;
  float* co_bet   = cpar + 550496;
  float* co_mea   = cpar + 550752;
  float* co_var   = cpar + 551008;

  float* cwT     = ws + 16 + 551264;                // 16384 f (w_g2 transposed)
  bf16*  wdefb   = (bf16*)(ws + 567664);            // 73728 f
  bf16*  woffb   = (bf16*)(ws + 641392);            // 36864 f
  bf16*  wg1b    = (bf16*)(ws + 678256);            // 73728 f
  bf16*  wcrossb = (bf16*)(ws + 751984);            // 65536 f
  bf16*  woutb   = (bf16*)(ws + 817520);            // 32768 f
  float* base    = ws + 850288;
  float* offp    = base;                    // 4 x 294912  = 1179648 f
  float* offc    = offp + 1179648;          // 294912 f
  float* abp     = offc + 294912;           // 4 x 1048576 = 4194304 f
  bf16*  xdirb   = (bf16*)(abp + 4194304);  // 4194304 hw = 2097152 f
  bf16*  xdenseb = (bf16*)(abp + 6291456);  // 4194304 hw = 2097152 f
  bf16*  xtb     = (bf16*)(abp + 8388608);  // 4194304 hw = 2097152 f
  bf16*  xab     = xdirb;                   // reuse (xdir dead after K3)

  ParamSrc ps;
  for (int i = 0; i < 18; i++) ps.p[i] = d_in[2 + i];

  k_detect<<<dim3(1), 256, 0, stream>>>((const unsigned short*)x, flag);
  k_convert<<<dim3(96, 24), 256, 0, stream>>>(ps, flag, cpar, wdefb, woffb,
                                              wg1b, wcrossb, woutb, cwT);
  k_xt<<<dim3(1024), 256, 0, stream>>>(x, flag, xtb);
  k_coff_m<<<dim3(256, 4), 256, 0, stream>>>(x, flag, woffb, offp);
  k_omerge<<<dim3(288), 256, 0, stream>>>(offp, cb_off, offc);
  k_deform<<<dim3(512, 4), 256, 0, stream>>>(xtb, offc, wdefb, xdirb);
  k_cross<<<dim3(256, 2), 256, 0, stream>>>(xdirb, x_prev, flag, wcrossb, xdenseb);
  k_g1_m<<<dim3(256, 4), 256, 0, stream>>>(xdenseb, wg1b, abp);
  k_attn<<<dim3(1024), 256, 0, stream>>>(abp, cb_g1, cg1_gam, cg1_bet, cg1_mea,
                                         cg1_var, cwT, cb_g2, xdenseb, xab);
  k_out<<<dim3(256, 2), 256, 0, stream>>>(xab, woutb, cb_out, co_gam, co_bet,
                                          co_mea, co_var, x, d_out, flag);
}

// Round 12
// 328.484 us; speedup vs baseline: 1.6446x; 1.0651x over previous
//
#include <hip/hip_runtime.h>
#include <hip/hip_bf16.h>

using bf16 = __hip_bfloat16;
typedef __attribute__((ext_vector_type(8))) short short8;
typedef __attribute__((ext_vector_type(4))) float f32x4;

__device__ __forceinline__ float b2f(bf16 v){ return __bfloat162float(v); }
__device__ __forceinline__ float sigf(float v){ return 1.f/(1.f + __expf(-v)); }
__device__ __forceinline__ float ldv(const float* p, int i){ return p[i]; }
__device__ __forceinline__ float ldv(const bf16* p, int i){ return b2f(p[i]); }
__device__ __forceinline__ void stv(float* p, int i, float v){ p[i] = v; }
__device__ __forceinline__ void stv(bf16* p, int i, float v){ p[i] = __float2bfloat16(v); }
__device__ __forceinline__ float bfe(short8 v, int j){
  unsigned short s = (unsigned short)v[j];
  return b2f(*(bf16*)&s);
}

__device__ __forceinline__ void ld2v(const float* p, float& a, float& b){
  float2 v = *(const float2*)p; a = v.x; b = v.y;
}
__device__ __forceinline__ void ld2v(const bf16* p, float& a, float& b){
  unsigned int u = *(const unsigned int*)p;
  unsigned short s0 = (unsigned short)(u & 0xFFFF), s1 = (unsigned short)(u >> 16);
  a = b2f(*(bf16*)&s0); b = b2f(*(bf16*)&s1);
}
__device__ __forceinline__ void ld8(const bf16* s, unsigned int* pk){
  short8 v = *(const short8*)s;
  #pragma unroll
  for (int e = 0; e < 4; e++)
    pk[e] = (unsigned int)(unsigned short)v[2*e]
          | ((unsigned int)(unsigned short)v[2*e+1] << 16);
}
__device__ __forceinline__ void ld8(const float* s, unsigned int* pk){
  f32x4 a = *(const f32x4*)s, c = *(const f32x4*)(s + 4);
  float vals[8] = {a[0],a[1],a[2],a[3],c[0],c[1],c[2],c[3]};
  #pragma unroll
  for (int e = 0; e < 4; e++){
    bf16 h0 = __float2bfloat16(vals[2*e]), h1 = __float2bfloat16(vals[2*e+1]);
    pk[e] = (unsigned int)*(unsigned short*)&h0
          | ((unsigned int)*(unsigned short*)&h1 << 16);
  }
}

// ---------------------------------------------------------------------------
// K0: dtype detect. flag=1 => inputs are f32.
// ---------------------------------------------------------------------------
__global__ __launch_bounds__(256) void k_detect(const unsigned short* xs, int* flag){
  __shared__ int cnt;
  if (threadIdx.x == 0) cnt = 0;
  __syncthreads();
  int local = 0;
  for (int i = threadIdx.x; i < 16384; i += 256){
    if (((xs[i] >> 7) & 0xFF) == 0xFF) local++;
  }
  if (local) atomicAdd(&cnt, local);
  __syncthreads();
  if (threadIdx.x == 0) *flag = (cnt > 0) ? 1 : 0;
}

// ---------------------------------------------------------------------------
// K0b: canonicalize params (R9 structure — passing).
// ---------------------------------------------------------------------------
struct ParamSrc { const void* p[18]; };

__global__ __launch_bounds__(256) void k_convert(ParamSrc ps, const int* flagp,
    float* cpar, bf16* wdefb, bf16* woffb, bf16* wg1b, bf16* wcrossb, bf16* woutb,
    float* cwT){
  static constexpr int n[24]   = {41472,18,147456,131072,147456,64,64,64,64,64,
                                  16384,256,65536,256,256,256,256,256,
                                  147456,73728,147456,131072,65536,16384};
  static constexpr int off[18] = {0,41472,41504,188960,320032,467488,467552,467616,
                                  467680,467744,467808,484192,484448,549984,550240,
                                  550496,550752,551008};
  const int s = blockIdx.y;
  const bool f32 = (*flagp != 0);
  if (s == 23){
    for (int i = blockIdx.x * 256 + threadIdx.x; i < 16384; i += gridDim.x * 256){
      const int c = i >> 8, co = i & 255;
      if (f32) cwT[i] = ((const float*)ps.p[10])[co * 64 + c];
      else     cwT[i] = b2f(((const bf16*)ps.p[10])[co * 64 + c]);
    }
    return;
  }
  if (s >= 18){
    static constexpr int srcs[5] = {2, 0, 4, 3, 12};
    const int src_slot = srcs[s - 18];
    bf16* dst = (s == 18) ? wdefb : (s == 19) ? woffb : (s == 20) ? wg1b
              : (s == 21) ? wcrossb : woutb;
    const int nsrc = (s == 19) ? 41472 : n[s];
    const bool remap = (s == 19 || s == 20);
    for (int i = blockIdx.x * 256 + threadIdx.x; i < n[s]; i += gridDim.x * 256){
      int srcIdx = i;
      if (remap){
        const int co = i / 2304, rem = i % 2304;
        const int chunk = rem / 288, r2 = rem % 288;
        const int tap = r2 >> 5, cl = r2 & 31;
        srcIdx = co * 2304 + (chunk * 32 + cl) * 9 + tap;
      }
      if (f32){
        const float* src = (const float*)ps.p[src_slot];
        dst[i] = (srcIdx < nsrc) ? __float2bfloat16(src[srcIdx]) : __float2bfloat16(0.f);
      } else {
        const bf16* src = (const bf16*)ps.p[src_slot];
        dst[i] = (srcIdx < nsrc) ? src[srcIdx] : __float2bfloat16(0.f);
      }
    }
    return;
  }
  float* dst = cpar + off[s];
  if (f32){
    const float* src = (const float*)ps.p[s];
    for (int i = blockIdx.x * 256 + threadIdx.x; i < n[s]; i += gridDim.x * 256)
      dst[i] = src[i];
  } else {
    const bf16* src = (const bf16*)ps.p[s];
    for (int i = blockIdx.x * 256 + threadIdx.x; i < n[s]; i += gridDim.x * 256)
      dst[i] = b2f(src[i]);
  }
}

// ---------------------------------------------------------------------------
// K1b: NHWC bf16 staging for deform gather: x_t[b][g][p=4096][cg=64].
// ---------------------------------------------------------------------------
template<typename T>
__device__ __forceinline__ void xt_body(const T* __restrict__ x, bf16* __restrict__ xt){
  __shared__ float lds[64][65];
  const int bx = blockIdx.x;
  const int b = bx >> 8, y = (bx >> 2) & 63, g = bx & 3;
  const int t = threadIdx.x;
  const int px = t & 63, cq = t >> 6;
  #pragma unroll
  for (int it = 0; it < 16; it++){
    const int ch = cq * 16 + it;
    lds[ch][px] = ldv(x, ((b * 256 + g * 64 + ch) * 64 + y) * 64 + px);
  }
  __syncthreads();
  const int ch = t & 63, pb = t >> 6;
  bf16* ob = xt + ((b * 4 + g) * 4096 + y * 64) * 64 + ch;
  #pragma unroll
  for (int i = 0; i < 16; i++){
    const int p = pb * 16 + i;
    ob[p * 64] = __float2bfloat16(lds[ch][p]);
  }
}

__global__ __launch_bounds__(256) void k_xt(const void* x, const int* flagp, bf16* xt){
  if (*flagp) xt_body((const float*)x, xt);
  else        xt_body((const bf16*)x, xt);
}

// ---------------------------------------------------------------------------
// conv3 RAW split-K, TILE-STAGED (R9 structure — passing).
// ---------------------------------------------------------------------------
template<typename T, int COT>
__device__ __forceinline__ void conv3_raw(const T* __restrict__ xin,
    const bf16* __restrict__ wb, float* __restrict__ outp, int co_lim,
    unsigned short* xt16, int cc_begin){
  const int bx = blockIdx.x;
  const int b = bx >> 6, y = bx & 63;
  const int t = threadIdx.x;
  const int l = t & 63, w = t >> 6;
  const int lm = l & 15, lq = l >> 4;
  const int px = w * 16 + lm;
  f32x4 acc[COT];
  #pragma unroll
  for (int m = 0; m < COT; m++) acc[m] = (f32x4){0.f,0.f,0.f,0.f};

  #pragma unroll
  for (int ch_i = 0; ch_i < 2; ch_i++){
    const int cc = cc_begin + ch_i * 32;
    __syncthreads();
    if (t < 96){
      const int c = t / 3, r = t - c * 3;
      xt16[c * 210 + r * 70 + 3]  = 0;
      xt16[c * 210 + r * 70 + 68] = 0;
    }
    #pragma unroll
    for (int it = 0; it < 3; it++){
      const int u = t + it * 256;
      const int pb = u & 7;
      const int cr = u >> 3;
      const int c = cr / 3, r = cr - c * 3;
      const int yy = y + r - 1;
      const int px0 = pb * 8;
      unsigned int pk[4];
      if ((unsigned)yy < 64u){
        ld8(xin + (b * 256 + cc + c) * 4096 + yy * 64 + px0, pk);
      } else {
        pk[0] = pk[1] = pk[2] = pk[3] = 0;
      }
      unsigned int* dp = (unsigned int*)(xt16 + c * 210 + r * 70 + 4 + px0);
      dp[0] = pk[0]; dp[1] = pk[1]; dp[2] = pk[2]; dp[3] = pk[3];
    }
    __syncthreads();
    const int chunkG = cc >> 5;
    const unsigned short* bt = xt16 + 3 + px;
    #pragma unroll
    for (int tap = 0; tap < 9; tap++){
      const int ti = tap / 3, tj = tap - ti * 3;
      short8 bfr;
      #pragma unroll
      for (int j = 0; j < 8; j++)
        bfr[j] = (short)bt[(lq * 8 + j) * 210 + ti * 70 + tj];
      #pragma unroll
      for (int m = 0; m < COT; m++){
        const bf16* ap = wb + (m * 16 + lm) * 2304 + chunkG * 288 + tap * 32 + lq * 8;
        short8 afr = *(const short8*)ap;
        acc[m] = __builtin_amdgcn_mfma_f32_16x16x32_bf16(afr, bfr, acc[m], 0, 0, 0);
      }
    }
  }
  const int p = y * 64 + px;
  #pragma unroll
  for (int m = 0; m < COT; m++){
    #pragma unroll
    for (int r = 0; r < 4; r++){
      const int co = m * 16 + lq * 4 + r;
      if (co >= co_lim) continue;
      outp[(b * co_lim + co) * 4096 + p] = acc[m][r];
    }
  }
}

__global__ __launch_bounds__(256) void k_coff_m(const void* x, const int* flagp,
    const bf16* woffb, float* offp){
  __shared__ __align__(16) unsigned short xtile[32 * 210];
  float* op = offp + blockIdx.y * 294912;
  const int cc0 = blockIdx.y * 64;
  if (*flagp) conv3_raw<float, 2>((const float*)x, woffb, op, 18, xtile, cc0);
  else        conv3_raw<bf16, 2>((const bf16*)x, woffb, op, 18, xtile, cc0);
}

__global__ __launch_bounds__(256) void k_g1_m(const bf16* xdense,
    const bf16* wg1b, float* abp){
  __shared__ __align__(16) unsigned short xtile[32 * 210];
  float* op = abp + blockIdx.y * 1048576;
  conv3_raw<bf16, 4>(xdense, wg1b, op, 64, xtile, blockIdx.y * 64);
}

// ---------------------------------------------------------------------------
// K1c: merge 4 offset partials + bias -> offc.
// ---------------------------------------------------------------------------
__global__ __launch_bounds__(256) void k_omerge(const float* __restrict__ offp,
    const float* __restrict__ cb, float* __restrict__ offc){
  const int i4 = (blockIdx.x * 256 + threadIdx.x) * 4;
  constexpr int PS = 294912;
  f32x4 a = *(const f32x4*)(offp + i4);
  f32x4 b = *(const f32x4*)(offp + PS + i4);
  f32x4 c = *(const f32x4*)(offp + 2 * PS + i4);
  f32x4 d = *(const f32x4*)(offp + 3 * PS + i4);
  const int co = (i4 >> 12) % 18;
  const float bias = cb[co];
  f32x4 r;
  #pragma unroll
  for (int j = 0; j < 4; j++) r[j] = ((a[j] + b[j]) + c[j]) + d[j] + bias;
  *(f32x4*)(offc + i4) = r;
}

// ---------------------------------------------------------------------------
// K2: deformable conv — merged single-pass bf16 NHWC gather (R10 structure,
// bf16 xdir out).
// ---------------------------------------------------------------------------
#define CROWM 600

__global__ __launch_bounds__(256) void k_deform(const bf16* __restrict__ xt,
    const float* __restrict__ offc, const bf16* __restrict__ wdefb,
    bf16* __restrict__ xdir){
  __shared__ __align__(16) unsigned short cols[32 * CROWM];
  const int g = blockIdx.y;
  const int q0 = blockIdx.x * 32;
  const int b = q0 >> 12, p0 = q0 & 4095;
  const int t = threadIdx.x;
  {
    const int pos = t & 31, u8 = t >> 5;
    const int c0 = u8 * 8;
    const int p = p0 + pos;
    const int y = p >> 6, xx = p & 63;
    const float* ob = offc + b * 18 * 4096 + p;
    const bf16* xg = xt + (b * 4 + g) * 4096 * 64;
    #pragma unroll
    for (int k = 0; k < 9; k++){
      float dy = ob[(2 * k) * 4096];
      float dx = ob[(2 * k + 1) * 4096];
      float py = (float)(y + k / 3 - 1) + dy;
      float px = (float)(xx + k % 3 - 1) + dx;
      float y0f = floorf(py), x0f = floorf(px);
      int y0 = (int)y0f, x0 = (int)x0f;
      float wy1 = py - y0f, wx1 = px - x0f;
      float wy0 = 1.f - wy1, wx0 = 1.f - wx1;
      bool vy0 = (unsigned)y0 < 64u, vy1 = (unsigned)(y0 + 1) < 64u;
      bool vx0 = (unsigned)x0 < 64u, vx1 = (unsigned)(x0 + 1) < 64u;
      float w00 = (vy0 && vx0) ? wy0 * wx0 : 0.f;
      float w01 = (vy0 && vx1) ? wy0 * wx1 : 0.f;
      float w10 = (vy1 && vx0) ? wy1 * wx0 : 0.f;
      float w11 = (vy1 && vx1) ? wy1 * wx1 : 0.f;
      int yc0 = min(max(y0, 0), 63), yc1 = min(max(y0 + 1, 0), 63);
      int xc0 = min(max(x0, 0), 63), xc1 = min(max(x0 + 1, 0), 63);
      int i00 = yc0 * 64 + xc0, i01 = yc0 * 64 + xc1;
      int i10 = yc1 * 64 + xc0, i11 = yc1 * 64 + xc1;
      short8 s00 = *(const short8*)(xg + i00 * 64 + c0);
      short8 s01 = *(const short8*)(xg + i01 * 64 + c0);
      short8 s10 = *(const short8*)(xg + i10 * 64 + c0);
      short8 s11 = *(const short8*)(xg + i11 * 64 + c0);
      #pragma unroll
      for (int j = 0; j < 8; j++){
        float val = w00 * bfe(s00, j) + w01 * bfe(s01, j)
                  + w10 * bfe(s10, j) + w11 * bfe(s11, j);
        bf16 hv = __float2bfloat16(val);
        cols[pos * CROWM + (c0 + j) * 9 + k] = *(unsigned short*)&hv;
      }
    }
  }
  __syncthreads();
  {
    const int w = t >> 6;
    const int l = t & 63;
    const int lrow = l & 15;
    const int lhi = l >> 4;
    f32x4 acc0 = {0.f, 0.f, 0.f, 0.f};
    f32x4 acc1 = {0.f, 0.f, 0.f, 0.f};
    const bf16* wr = wdefb + (g * 64 + w * 16 + lrow) * 576;
    const unsigned short* b0p = cols + lrow * CROWM;
    const unsigned short* b1p = cols + (16 + lrow) * CROWM;
    #pragma unroll 2
    for (int kk = 0; kk < 576; kk += 32){
      int ko = kk + lhi * 8;
      short8 a  = *(const short8*)(wr + ko);
      short8 b0 = *(const short8*)(b0p + ko);
      short8 b1 = *(const short8*)(b1p + ko);
      acc0 = __builtin_amdgcn_mfma_f32_16x16x32_bf16(a, b0, acc0, 0, 0, 0);
      acc1 = __builtin_amdgcn_mfma_f32_16x16x32_bf16(a, b1, acc1, 0, 0, 0);
    }
    const int co_base = g * 64 + w * 16 + lhi * 4;
    #pragma unroll
    for (int r = 0; r < 4; r++){
      bf16* xo = xdir + (b * 256 + co_base + r) * 4096 + p0 + lrow;
      xo[0]  = __float2bfloat16(acc0[r]);
      xo[16] = __float2bfloat16(acc1[r]);
    }
  }
}

// ---------------------------------------------------------------------------
// K3: 1x1 conv concat([x_dir, x_prev]) * w_cross — MFMA.
// R12: grid (256,4) COT=4 (4 blocks/CU) + async-stage: per chunk,
// {barrier; ds_write(pk); barrier; issue loads chunk+1 -> pk; MFMA}.
// Loads fly under MFMA; single LDS buffer; numerics bit-identical.
// ---------------------------------------------------------------------------
template<typename T>
__device__ __forceinline__ void cross_load(const bf16* __restrict__ xdir,
    const T* __restrict__ xprev, int b, int y, int pos2, int cq, int cc,
    unsigned int* pk){
  #pragma unroll
  for (int c8 = 0; c8 < 8; c8++){
    const int ci = cc + cq * 8 + c8;
    if (ci < 256){
      pk[c8] = *(const unsigned int*)(xdir + (b * 256 + ci) * 4096 + y * 64 + 2 * pos2);
    } else {
      float v0, v1;
      ld2v(xprev + (b * 256 + (ci - 256)) * 4096 + y * 64 + 2 * pos2, v0, v1);
      bf16 h0 = __float2bfloat16(v0), h1 = __float2bfloat16(v1);
      pk[c8] = (unsigned int)*(unsigned short*)&h0
             | ((unsigned int)*(unsigned short*)&h1 << 16);
    }
  }
}

template<typename T>
__device__ __forceinline__ void cross_mfma_body(const bf16* __restrict__ xdir,
    const T* __restrict__ xprev, const bf16* __restrict__ wb,
    bf16* __restrict__ xdense, unsigned short* cols){
  const int bx = blockIdx.x;
  const int b = bx >> 6, y = bx & 63;
  const int co0 = blockIdx.y * 64;
  const int t = threadIdx.x;
  const int l = t & 63, w = t >> 6;
  const int lm = l & 15, lq = l >> 4;
  const int pos2 = t & 31, cq = t >> 5;
  unsigned int* cols32 = (unsigned int*)cols;
  f32x4 acc[4];
  #pragma unroll
  for (int m = 0; m < 4; m++) acc[m] = (f32x4){0.f,0.f,0.f,0.f};
  unsigned int pk[8];
  cross_load(xdir, xprev, b, y, pos2, cq, 0, pk);

  for (int c = 0; c < 8; c++){
    __syncthreads();
    #pragma unroll
    for (int c8 = 0; c8 < 8; c8++)
      cols32[(cq * 8 + c8) * 34 + pos2] = pk[c8];
    __syncthreads();
    if (c < 7) cross_load(xdir, xprev, b, y, pos2, cq, (c + 1) * 64, pk);
    const int cc = c * 64;
    #pragma unroll
    for (int kk = 0; kk < 64; kk += 32){
      short8 bfr;
      #pragma unroll
      for (int j = 0; j < 8; j++)
        bfr[j] = (short)cols[(kk + lq * 8 + j) * 68 + w * 16 + lm];
      #pragma unroll
      for (int m = 0; m < 4; m++){
        const bf16* ap = wb + (co0 + m * 16 + lm) * 512 + cc + kk + lq * 8;
        short8 afr = *(const short8*)ap;
        acc[m] = __builtin_amdgcn_mfma_f32_16x16x32_bf16(afr, bfr, acc[m], 0, 0, 0);
      }
    }
  }
  const int p = y * 64 + w * 16 + lm;
  #pragma unroll
  for (int m = 0; m < 4; m++){
    #pragma unroll
    for (int r = 0; r < 4; r++){
      const int co = co0 + m * 16 + lq * 4 + r;
      xdense[(b * 256 + co) * 4096 + p] = __float2bfloat16(acc[m][r]);
    }
  }
}

__global__ __launch_bounds__(256) void k_cross(const bf16* xdir, const void* xprev,
    const int* flagp, const bf16* wcb, bf16* xdense){
  __shared__ __align__(16) unsigned short cols[64 * 68];
  if (*flagp) cross_mfma_body(xdir, (const float*)xprev, wcb, xdense, cols);
  else        cross_mfma_body(xdir, (const bf16*)xprev, wcb, xdense, cols);
}

// ---------------------------------------------------------------------------
// K5: attn (R8 structure). xdense bf16; xa bf16.
// ---------------------------------------------------------------------------
__global__ __launch_bounds__(256) void k_attn(const float* __restrict__ abp,
    const float* __restrict__ cb1, const float* __restrict__ gam,
    const float* __restrict__ bet, const float* __restrict__ mea,
    const float* __restrict__ var, const float* __restrict__ cwT,
    const float* __restrict__ cb2, const bf16* __restrict__ xdense,
    bf16* __restrict__ xa){
  __shared__ float a_s[64][17];
  const int bx = blockIdx.x;
  const int b = bx >> 8, pc = bx & 255;
  const int p0 = pc * 16;
  const int t = threadIdx.x;
  constexpr int PS = 1048576;
  {
    const int ch = t >> 2;
    const int px0 = (t & 3) * 4;
    const float inv = gam[ch] * rsqrtf(var[ch] + 1e-5f);
    const float sh  = bet[ch] - mea[ch] * inv;
    const float bias = cb1[ch];
    const int ai = (b * 64 + ch) * 4096 + p0 + px0;
    #pragma unroll
    for (int j = 0; j < 4; j++){
      float s = ((abp[ai + j] + abp[PS + ai + j]) + abp[2 * PS + ai + j])
              + abp[3 * PS + ai + j];
      s += bias;
      s = s * inv + sh;
      s = s * sigf(s);
      a_s[ch][px0 + j] = s;
    }
  }
  __syncthreads();
  const int co = t;
  float acc[16];
  #pragma unroll
  for (int i = 0; i < 16; i++) acc[i] = 0.f;
  for (int c = 0; c < 64; c++){
    const float wv = cwT[c * 256 + co];
    #pragma unroll
    for (int i = 0; i < 16; i++) acc[i] += wv * a_s[c][i];
  }
  const float bias2 = cb2[co];
  const int base = (b * 256 + co) * 4096 + p0;
  #pragma unroll
  for (int i = 0; i < 16; i++){
    float attn = sigf(acc[i] + bias2);
    xa[base + i] = __float2bfloat16(b2f(xdense[base + i]) * attn);
  }
}

// ---------------------------------------------------------------------------
// K6: 1x1 conv 256->256 + bias + BN + SiLU + residual — MFMA.
// R12: grid (256,4) COT=4 + async-stage (same template as k_cross).
// ---------------------------------------------------------------------------
__device__ __forceinline__ void out_load(const bf16* __restrict__ xa,
    int b, int y, int pos2, int cq, int cc, unsigned int* pk){
  #pragma unroll
  for (int c8 = 0; c8 < 8; c8++){
    const int ci = cc + cq * 8 + c8;
    pk[c8] = *(const unsigned int*)(xa + (b * 256 + ci) * 4096 + y * 64 + 2 * pos2);
  }
}

template<typename T>
__device__ __forceinline__ void out_mfma_body(const bf16* __restrict__ xa,
    const bf16* __restrict__ wb, const float* __restrict__ cbv,
    const float* __restrict__ gam, const float* __restrict__ bet,
    const float* __restrict__ mea, const float* __restrict__ var,
    const T* __restrict__ xres, T* __restrict__ outp, unsigned short* cols){
  const int bx = blockIdx.x;
  const int b = bx >> 6, y = bx & 63;
  const int co0 = blockIdx.y * 64;
  const int t = threadIdx.x;
  const int l = t & 63, w = t >> 6;
  const int lm = l & 15, lq = l >> 4;
  const int pos2 = t & 31, cq = t >> 5;
  unsigned int* cols32 = (unsigned int*)cols;
  f32x4 acc[4];
  #pragma unroll
  for (int m = 0; m < 4; m++) acc[m] = (f32x4){0.f,0.f,0.f,0.f};
  unsigned int pk[8];
  out_load(xa, b, y, pos2, cq, 0, pk);

  for (int c = 0; c < 4; c++){
    __syncthreads();
    #pragma unroll
    for (int c8 = 0; c8 < 8; c8++)
      cols32[(cq * 8 + c8) * 34 + pos2] = pk[c8];
    __syncthreads();
    if (c < 3) out_load(xa, b, y, pos2, cq, (c + 1) * 64, pk);
    const int cc = c * 64;
    #pragma unroll
    for (int kk = 0; kk < 64; kk += 32){
      short8 bfr;
      #pragma unroll
      for (int j = 0; j < 8; j++)
        bfr[j] = (short)cols[(kk + lq * 8 + j) * 68 + w * 16 + lm];
      #pragma unroll
      for (int m = 0; m < 4; m++){
        const bf16* ap = wb + (co0 + m * 16 + lm) * 256 + cc + kk + lq * 8;
        short8 afr = *(const short8*)ap;
        acc[m] = __builtin_amdgcn_mfma_f32_16x16x32_bf16(afr, bfr, acc[m], 0, 0, 0);
      }
    }
  }
  const int p = y * 64 + w * 16 + lm;
  #pragma unroll
  for (int m = 0; m < 4; m++){
    #pragma unroll
    for (int r = 0; r < 4; r++){
      const int co = co0 + m * 16 + lq * 4 + r;
      float inv = gam[co] * rsqrtf(var[co] + 1e-5f);
      float v = acc[m][r] + cbv[co];
      v = v * inv + (bet[co] - mea[co] * inv);
      v = v * sigf(v);
      const int idx = (b * 256 + co) * 4096 + p;
      stv(outp, idx, v + ldv(xres, idx));
    }
  }
}

__global__ __launch_bounds__(256) void k_out(const bf16* xa, const bf16* wob,
    const float* cb, const float* gam, const float* bet, const float* mea,
    const float* var, const void* xres, void* out, const int* flagp){
  __shared__ __align__(16) unsigned short cols[64 * 68];
  if (*flagp) out_mfma_body(xa, wob, cb, gam, bet, mea, var,
                            (const float*)xres, (float*)out, cols);
  else        out_mfma_body(xa, wob, cb, gam, bet, mea, var,
                            (const bf16*)xres, (bf16*)out, cols);
}

// ---------------------------------------------------------------------------
extern "C" void kernel_launch(void* const* d_in, const int* in_sizes, int n_in,
                              void* d_out, int out_size, void* d_ws, size_t ws_size,
                              hipStream_t stream) {
  const void* x      = d_in[0];
  const void* x_prev = d_in[1];

  float* ws   = (float*)d_ws;
  int*   flag = (int*)ws;                 // ws[0..15] reserved
  float* cpar = ws + 16;                  // canonical fp32 params (551264 f)
  float* cb_off   = cpar + 41472;
  float* cb_g1    = cpar + 467488;
  float* cg1_gam  = cpar + 467552;
  float* cg1_bet  = cpar + 467616;
  float* cg1_mea  = cpar + 467680;
  float* cg1_var  = cpar + 467744;
  float* cb_g2    = cpar + 484192;
  float* cb_out   = cpar + 549984;
  float* co_gam   = cpar + 550240;
  float* co_bet   = cpar + 550496;
  float* co_mea   = cpar + 550752;
  float* co_var   = cpar + 551008;

  float* cwT     = ws + 16 + 551264;                // 16384 f (w_g2 transposed)
  bf16*  wdefb   = (bf16*)(ws + 567664);            // 73728 f
  bf16*  woffb   = (bf16*)(ws + 641392);            // 36864 f
  bf16*  wg1b    = (bf16*)(ws + 678256);            // 73728 f
  bf16*  wcrossb = (bf16*)(ws + 751984);            // 65536 f
  bf16*  woutb   = (bf16*)(ws + 817520);            // 32768 f
  float* base    = ws + 850288;
  float* offp    = base;                    // 4 x 294912  = 1179648 f
  float* offc    = offp + 1179648;          // 294912 f
  float* abp     = offc + 294912;           // 4 x 1048576 = 4194304 f
  bf16*  xdirb   = (bf16*)(abp + 4194304);  // 4194304 hw = 2097152 f
  bf16*  xdenseb = (bf16*)(abp + 6291456);  // 4194304 hw = 2097152 f
  bf16*  xtb     = (bf16*)(abp + 8388608);  // 4194304 hw = 2097152 f
  bf16*  xab     = xdirb;                   // reuse (xdir dead after K3)

  ParamSrc ps;
  for (int i = 0; i < 18; i++) ps.p[i] = d_in[2 + i];

  k_detect<<<dim3(1), 256, 0, stream>>>((const unsigned short*)x, flag);
  k_convert<<<dim3(96, 24), 256, 0, stream>>>(ps, flag, cpar, wdefb, woffb,
                                              wg1b, wcrossb, woutb, cwT);
  k_xt<<<dim3(1024), 256, 0, stream>>>(x, flag, xtb);
  k_coff_m<<<dim3(256, 4), 256, 0, stream>>>(x, flag, woffb, offp);
  k_omerge<<<dim3(288), 256, 0, stream>>>(offp, cb_off, offc);
  k_deform<<<dim3(512, 4), 256, 0, stream>>>(xtb, offc, wdefb, xdirb);
  k_cross<<<dim3(256, 4), 256, 0, stream>>>(xdirb, x_prev, flag, wcrossb, xdenseb);
  k_g1_m<<<dim3(256, 4), 256, 0, stream>>>(xdenseb, wg1b, abp);
  k_attn<<<dim3(1024), 256, 0, stream>>>(abp, cb_g1, cg1_gam, cg1_bet, cg1_mea,
                                         cg1_var, cwT, cb_g2, xdenseb, xab);
  k_out<<<dim3(256, 4), 256, 0, stream>>>(xab, woutb, cb_out, co_gam, co_bet,
                                          co_mea, co_var, x, d_out, flag);
}